// Round 9
// baseline (749.636 us; speedup 1.0000x reference)
//
#include <hip/hip_runtime.h>
#include <hip/hip_fp16.h>

// Problem constants: B=64, N=256, F_IN=768, F_OUT=256
#define NB    64
#define NN    256
#define FIN   768
#define FOUT  256

typedef _Float16 half8v __attribute__((ext_vector_type(8)));
typedef float    float4v __attribute__((ext_vector_type(4)));

// f32 -> fp8 e4m3 (OCP, RNE) single value
__device__ inline unsigned char enc8(float v){
#if __has_builtin(__builtin_amdgcn_cvt_pk_fp8_f32)
  return (unsigned char)(__builtin_amdgcn_cvt_pk_fp8_f32(v, v, 0, false) & 0xFF);
#else
  float best = 1e30f; unsigned char bc = 0;
  for (int c = 0; c < 256; c++){
    if ((c & 0x7F) == 0x7F) continue;            // NaN codes
    int e = (c >> 3) & 15, mnt = c & 7;
    float mag = e ? ldexpf(1.f + mnt*0.125f, e-7) : ldexpf(mnt*0.125f, -6);
    float d = (c >> 7) ? -mag : mag;
    float err = fabsf(v - d);
    if (err < best){ best = err; bc = (unsigned char)c; }
  }
  return bc;
#endif
}

__device__ inline float4v mfma_fp8(long long a, long long b, float4v c){
  return __builtin_amdgcn_mfma_f32_16x16x32_fp8_fp8(a, b, c, 0, 0, 0);
}
__device__ inline float4v mfma_f16(half8v a, half8v b, float4v c){
  return __builtin_amdgcn_mfma_f32_16x16x32_f16(a, b, c, 0, 0, 0);
}

// Raw barrier: LDS-visibility only (lgkmcnt drain); global loads stay in
// flight. All cross-wave edges in the scan are LDS.
#define RAW_BAR() do { \
    asm volatile("s_waitcnt lgkmcnt(0)" ::: "memory"); \
    __builtin_amdgcn_s_barrier(); \
  } while (0)

// ---------------------------------------------------------------------------
// prep: f16 conversions for the big x-side GEMMs.
// ---------------------------------------------------------------------------
__global__ __launch_bounds__(256) void prep_kernel(
    const float* __restrict__ emb_W, const float* __restrict__ ioux_W,
    const float* __restrict__ ioux_b, const float* __restrict__ coux_W,
    const float* __restrict__ coux_b,
    _Float16* __restrict__ embW16, _Float16* __restrict__ Wcat16,
    float* __restrict__ biascat)
{
  int idx = blockIdx.x*256 + threadIdx.x;
  if (idx < 196608) { embW16[idx] = (_Float16)emb_W[idx]; return; }
  idx -= 196608;
  if (idx < 196608) {
    int o = idx >> 8, k = idx & 255;
    float v = (o < 512) ? ioux_W[o*256 + k] : coux_W[(o-512)*256 + k];
    Wcat16[idx] = (_Float16)v; return;
  }
  idx -= 196608;
  if (idx < 768) { biascat[idx] = (idx < 512) ? ioux_b[idx] : coux_b[idx-512]; return; }
}

// ---------------------------------------------------------------------------
// quant: per-output-row fp8 e4m3 quantization of iouh_W / couh_W in the
// MFMA swizzled layout. invrs[o] = 1/(rowscale*16).
// ---------------------------------------------------------------------------
__global__ __launch_bounds__(256) void quant_kernel(
    const float* __restrict__ iouh_W, const float* __restrict__ couh_W,
    unsigned char* __restrict__ iouh8, unsigned char* __restrict__ couh8,
    float* __restrict__ invrs_iou, float* __restrict__ invrs_cou)
{
  const int row = blockIdx.x;       // 0..767
  const int t   = threadIdx.x;      // 0..255 (k index)
  const bool is_iou = (row < 512);
  const int rl = is_iou ? row : row - 512;
  const float w = is_iou ? iouh_W[(size_t)rl*256 + t] : couh_W[(size_t)rl*256 + t];

  __shared__ float sm[256];
  sm[t] = fabsf(w);
  __syncthreads();
  for (int s = 128; s > 0; s >>= 1){
    if (t < s) sm[t] = fmaxf(sm[t], sm[t+s]);
    __syncthreads();
  }
  const float mx = sm[0];
  const float rs = (mx > 1e-20f) ? (240.0f / mx) : 1.0f;
  const unsigned char byte = enc8(w * rs);
  const int off = ((rl>>4)*8 + (t>>5))*512 + ((t>>3)&3)*128 + (rl&15)*8 + (t&7);
  if (is_iou) iouh8[off] = byte; else couh8[off] = byte;
  if (t == 0){
    const float inv = 1.0f / (rs * 16.0f);
    if (is_iou) invrs_iou[rl] = inv; else invrs_cou[rl] = inv;
  }
}

// ---------------------------------------------------------------------------
// degmask: one row-major read of adj + LDS bit transpose.
// ---------------------------------------------------------------------------
__global__ __launch_bounds__(256) void degmask_kernel(
    const float* __restrict__ adj, unsigned int* __restrict__ maskw,
    float* __restrict__ dinv)
{
  const int b = blockIdx.x, t = threadIdx.x;
  __shared__ unsigned int rb[256][8];     // rb[row j][i>>5] bit (i&31)
  const float* rowp = adj + (size_t)b*NN*NN + (size_t)t*NN;
  float s = 0.f;
  #pragma unroll
  for (int qc = 0; qc < 8; qc++){
    unsigned int w = 0;
    const float4* rp = (const float4*)(rowp + qc*32);
    #pragma unroll
    for (int j4 = 0; j4 < 8; j4++){
      float4 v = rp[j4];
      s += v.x + v.y + v.z + v.w;
      const int sh = j4*4;
      w |= (v.x != 0.f ? 1u : 0u) << sh;
      w |= (v.y != 0.f ? 1u : 0u) << (sh+1);
      w |= (v.z != 0.f ? 1u : 0u) << (sh+2);
      w |= (v.w != 0.f ? 1u : 0u) << (sh+3);
    }
    rb[t][qc] = w;
  }
  dinv[b*NN + t] = (s != 0.f) ? 1.0f/s : 0.0f;
  __syncthreads();
  // maskw[b][i][q] bit jj = adj[32q+jj][i] = rb[32q+jj][i>>5] bit (i&31)
  #pragma unroll
  for (int qc = 0; qc < 8; qc++){
    unsigned int w = 0;
    #pragma unroll
    for (int jj = 0; jj < 32; jj++)
      w |= ((rb[qc*32 + jj][t>>5] >> (t&31)) & 1u) << jj;
    maskw[((size_t)b*NN + t)*8 + qc] = w;
  }
}

// ---------------------------------------------------------------------------
// GEMM (unchanged, validated): C = A @ Bw^T (+bias), C f16.
// ---------------------------------------------------------------------------
template<int AF32>
__global__ __launch_bounds__(256) void gemm16_kernel(
    const void* __restrict__ Aq, const _Float16* __restrict__ Bw,
    _Float16* __restrict__ Cout, const float* __restrict__ bias,
    int M, int N, int K, int ldc)
{
  const int wave = threadIdx.x >> 6;
  const int lane = threadIdx.x & 63;
  const int m0 = (blockIdx.x*4 + wave)*16;
  const int n0 = blockIdx.y*64;
  const int mrow = m0 + (lane & 15);
  const int kgrp = lane >> 4;
  float4v acc[4];
  #pragma unroll
  for (int nt = 0; nt < 4; nt++) acc[nt] = (float4v){0.f,0.f,0.f,0.f};

  for (int k0 = 0; k0 < K; k0 += 32){
    const int ka = k0 + kgrp*8;
    half8v af;
    if (AF32){
      const float* A = (const float*)Aq;
      const float4* ap = (const float4*)(A + (size_t)mrow*K + ka);
      float4 a0 = ap[0], a1 = ap[1];
      af[0]=(_Float16)a0.x; af[1]=(_Float16)a0.y; af[2]=(_Float16)a0.z; af[3]=(_Float16)a0.w;
      af[4]=(_Float16)a1.x; af[5]=(_Float16)a1.y; af[6]=(_Float16)a1.z; af[7]=(_Float16)a1.w;
    } else {
      const _Float16* A = (const _Float16*)Aq;
      af = *(const half8v*)(A + (size_t)mrow*K + ka);
    }
    #pragma unroll
    for (int nt = 0; nt < 4; nt++){
      const int ncol = n0 + nt*16 + (lane & 15);
      half8v bf = *(const half8v*)(Bw + (size_t)ncol*K + ka);
      acc[nt] = __builtin_amdgcn_mfma_f32_16x16x32_f16(af, bf, acc[nt], 0, 0, 0);
    }
  }
  #pragma unroll
  for (int nt = 0; nt < 4; nt++){
    const int ncol = n0 + nt*16 + (lane & 15);
    const float bv = bias ? bias[ncol] : 0.f;
    #pragma unroll
    for (int r = 0; r < 4; r++){
      const int orow = m0 + (lane>>4)*4 + r;
      Cout[(size_t)orow*ldc + ncol] = (_Float16)(acc[nt][r] + bv);
    }
  }
}

// ---------------------------------------------------------------------------
// transp: HcT[b][feat][node] = Hc[b][node][feat] (f16), coalesced both sides.
// ---------------------------------------------------------------------------
__global__ __launch_bounds__(256) void transp_kernel(
    const _Float16* __restrict__ Hc, _Float16* __restrict__ HcT)
{
  const int b = blockIdx.x, fg = blockIdx.y;   // feature group of 32
  const int t = threadIdx.x;
  __shared__ _Float16 tile[32][264];
  #pragma unroll
  for (int pass = 0; pass < 4; pass++){
    const int n  = pass*64 + (t>>2);
    const int f8 = (t&3)*8;
    const half8v v = *(const half8v*)(Hc + (size_t)(b*NN + n)*FOUT + fg*32 + f8);
    #pragma unroll
    for (int e = 0; e < 8; e++) tile[f8+e][n] = v[e];
  }
  __syncthreads();
  const int f = t>>3, ch = t&7;
  _Float16* dst = HcT + ((size_t)b*FOUT + fg*32 + f)*NN + ch*32;
  #pragma unroll
  for (int k = 0; k < 4; k++)
    *(half8v*)(dst + k*8) = *(const half8v*)(&tile[f][ch*32 + k*8]);
}

// ---------------------------------------------------------------------------
// scan R16 = R15 + {critical-path restructure}. R15 post-mortem: global-load
// handling exonerated (3 null edits); residual is the serial dependent chain
// per phase. Changes (same-wave-safe, numerics preserved):
//  1. split-K MFMA chains: iou 4x8-deep -> 8x4-deep (+add); cou 2x8 -> 4x4.
//  2. agg off the critical path: correction MFMA for column i+1 (mask bits
//     j<i, all deltas final) + B_tile[li+1] prefetch run INSIDE iou phase
//     (independent of iou results). At iter top, xp(i) finishes with just
//     dT[f][li-1] f16 read + scalar FMA (late j=i-1 term) + enc8.
//  3. hnT removed: boundary fold = Hreg += dT (f16 add; consistent with the
//     intra-tile he+dT math). One less LDS write/iter, -20KB LDS.
// LDS map (dynamic, 66560 B):
//   [0)     B_tile f32 [32 nodes] stride 1040B  33280
//   [33280) dT  f16 [256 f] stride 80B          20480
//   [53760) xp32 (256 f32)  1024
//   [54784) xp8  (256 B)     256
//   [55040) p8   (256 B)     256
//   [55296) z    (256 f32)  1024
//   [56320) pm   (256 f32)  1024
//   [57344) mask u32 [256][8] 8192
//   [65536) dinv f32 [256]   1024
// ---------------------------------------------------------------------------
#define OFF_BT   0
#define OFF_DT   33280
#define OFF_XP32 53760
#define OFF_XP8  54784
#define OFF_P8   55040
#define OFF_Z    55296
#define OFF_PM   56320
#define OFF_MASK 57344
#define OFF_DINV 65536
#define SCAN_LDS 66560

__global__ __launch_bounds__(512, 2)
void scan_kernel(
    const _Float16* __restrict__ Hc,    // [B*N][256] f16 = h_e (row-major)
    const _Float16* __restrict__ HcT,   // [B][256 feat][256 node] f16
    const _Float16* __restrict__ OUTX,  // [B*N][768] f16: [iou_x ; cou_x]
    const unsigned char* __restrict__ iouh8,  // swizzled fp8 [512][256]
    const unsigned char* __restrict__ couh8,  // swizzled fp8 [256][256]
    const float* __restrict__ invrs_iou,      // [512]
    const float* __restrict__ invrs_cou,      // [256]
    const float* __restrict__ dinv,     // [B*N]
    const unsigned int* __restrict__ maskw, // [B*N][8]
    const float* __restrict__ iouh_b,   // [512]
    const float* __restrict__ couh_b,   // [256]
    const float* __restrict__ fc_W,     // [2][256]
    const float* __restrict__ fc_b,     // [2]
    float* __restrict__ out)            // [B][2]
{
  const int b    = blockIdx.x;
  const int t    = threadIdx.x;        // 0..511
  const int wave = t >> 6;             // 0..7
  const int lane = t & 63;
  const int q    = lane >> 4;          // k-octet within MFMA frags
  const int r    = lane & 15;          // row/col index within MFMA tile
  const int f0   = 32*wave;            // wave's feature-slice base

  extern __shared__ __align__(16) char smem[];
  float*         sh_xp32 = (float*)(smem + OFF_XP32);
  unsigned char* sh_xp8  = (unsigned char*)(smem + OFF_XP8);
  unsigned char* sh_p8   = (unsigned char*)(smem + OFF_P8);
  float*         sh_z    = (float*)(smem + OFF_Z);
  float*         sh_pm   = (float*)(smem + OFF_PM);
  unsigned int*  sh_mask = (unsigned int*)(smem + OFF_MASK);
  float*         sh_dinv = (float*)(smem + OFF_DINV);

  // ---- one-time staging: zero delta-tile (5120 dw), mask words, dinv ----
  #pragma unroll
  for (int k = 0; k < 10; k++)
    ((unsigned int*)(smem + OFF_DT))[k*512 + t] = 0u;
  {
    const unsigned int* mg = maskw + ((size_t)b*NN)*8;
    #pragma unroll
    for (int k = 0; k < 4; k++) sh_mask[k*512 + t] = mg[k*512 + t];
    if (t < 256) sh_dinv[t] = dinv[(size_t)b*NN + t];
  }

  // ---- Hreg[g][ks]: H^T[f0+16g+r][ks*32 + q*8 + e] (64 VGPR) ----
  half8v Hreg[2][8];
  #pragma unroll
  for (int g = 0; g < 2; g++){
    const _Float16* hp = HcT + ((size_t)b*FOUT + f0 + 16*g + r)*NN + q*8;
    #pragma unroll
    for (int ks = 0; ks < 8; ks++)
      Hreg[g][ks] = *(const half8v*)(hp + ks*32);
  }

  // ---- recurrent weight frags (loop-invariant) ----
  long long ifrag[4][8];
  #pragma unroll
  for (int tt = 0; tt < 4; tt++)
    #pragma unroll
    for (int kc = 0; kc < 8; kc++)
      ifrag[tt][kc] = *(const long long*)(iouh8 + (size_t)(((4*wave+tt)*8 + kc)*512) + q*128 + r*8);
  long long cfrag[2][8];
  #pragma unroll
  for (int tt = 0; tt < 2; tt++)
    #pragma unroll
    for (int kc = 0; kc < 8; kc++)
      cfrag[tt][kc] = *(const long long*)(couh8 + (size_t)(((2*wave+tt)*8 + kc)*512) + q*128 + r*8);

  // ---- per-lane output assignments ----
  const int o1    = 64*wave + 16*(r>>2) + q*4 + (r&3);       // iou: 1/lane
  const int o_upd = 32*wave + 16*((r>>2)&1) + q*4 + (r&3);   // cou: lanes r<8
  const float bi1 = iouh_b[o1];
  const float vi1 = invrs_iou[o1];
  const float bcou_l = couh_b[o_upd];
  const float invc_l = invrs_cou[o_upd];
  float pmax = -1e30f;

  // ---- prologue prefetch: row 0 operands ----
  _Float16 pf_oxi = OUTX[(size_t)b*NN*768 + o1];
  _Float16 pf_oxc = OUTX[(size_t)b*NN*768 + 512 + o_upd];
  _Float16 pf_he  = Hc[(size_t)b*NN*FOUT + o_upd];

  __syncthreads();   // staging done (full barrier once is fine)
  unsigned int wl_cur = sh_mask[0];

  // pipelined per-lane state (computed in iou phase for the NEXT column)
  float cp[2]  = {0.f, 0.f};   // intra-tile correction partial (j < i)
  float btn[2] = {0.f, 0.f};   // B_tile[li][f_agg] prefetch

  #pragma unroll 1
  for (int i = 0; i < NN; i++){
    const int li = i & 31;

    // ======== tile boundary (no barrier: all edges same-wave) ========
    if (li == 0){
      const int tile = i >> 5;
      if (tile > 0){
        const int tprev = tile - 1;
        #pragma unroll
        for (int g = 0; g < 2; g++){
          // fold: Hreg += delta (dT holds full prev-tile deltas)
          const half8v dvv = *(const half8v*)(smem + OFF_DT + (f0 + 16*g + r)*80 + q*16);
          #pragma unroll
          for (int ks = 0; ks < 8; ks++) if (ks == tprev) Hreg[g][ks] = Hreg[g][ks] + dvv;
        }
      }
      float4v bacc[2][2];
      #pragma unroll
      for (int rt = 0; rt < 2; rt++)
        #pragma unroll
        for (int g = 0; g < 2; g++) bacc[rt][g] = (float4v){0.f,0.f,0.f,0.f};
      #pragma unroll
      for (int rt = 0; rt < 2; rt++){
        #pragma unroll
        for (int ks = 0; ks < 8; ks++){
          const unsigned int wm = sh_mask[(i + rt*16 + r)*8 + ks];
          half8v am;
          #pragma unroll
          for (int e = 0; e < 8; e++)
            am[e] = (_Float16)((wm >> (q*8 + e)) & 1u);
          bacc[rt][0] = mfma_f16(am, Hreg[0][ks], bacc[rt][0]);
          bacc[rt][1] = mfma_f16(am, Hreg[1][ks], bacc[rt][1]);
        }
      }
      #pragma unroll
      for (int rt = 0; rt < 2; rt++)
        #pragma unroll
        for (int g = 0; g < 2; g++)
          #pragma unroll
          for (int jj = 0; jj < 4; jj++)
            *(float*)(smem + (rt*16 + q*4 + jj)*1040 + (f0 + 16*g + r)*4) = bacc[rt][g][jj];
      // fresh B_tile row 0 for this lane's features; cp = 0
      #pragma unroll
      for (int g = 0; g < 2; g++){
        btn[g] = *(const float*)(smem + /*li=0*/ (f0 + 16*g + r)*4);
        cp[g] = 0.f;
      }
    }
    // ================================================================

    const unsigned int wl_next = sh_mask[((i+1)&255)*8 + (((i+1)>>5)&7)];

    // consume prefetched global operands; issue next row's
    const float oxi = (float)pf_oxi;
    const float oxc = (float)pf_oxc;
    const float he  = (float)pf_he;
    {
      const size_t rown = (size_t)b*NN + ((i+1) & 255);
      pf_oxi = OUTX[rown*768 + o1];
      pf_oxc = OUTX[rown*768 + 512 + o_upd];
      pf_he  = Hc[rown*FOUT + o_upd];
    }
    const float dv = sh_dinv[i];

    // ---- xp finish (short critical path): cp + late term + B_tile ----
    {
      #pragma unroll
      for (int g = 0; g < 2; g++){
        const int fg = f0 + 16*g + r;
        float corr = cp[g];
        if (li > 0 && ((wl_cur >> (li-1)) & 1u))
          corr += (float)*(const _Float16*)(smem + OFF_DT + fg*80 + (li-1)*2);
        const float xp = (btn[g] + corr) * dv;
        if (q == 0)      sh_xp32[fg] = xp;
        else if (q == 1) sh_xp8[fg] = enc8(xp * 16.f);
      }
    }
    RAW_BAR();                                          // B2 (xp cross-wave)

    // ---- iou matvec: 32 fp8 MFMAs as 8 chains of 4 + overlapped extras ----
    float xpv_pre = 0.f;
    {
      float4v iacc[4][2];
      #pragma unroll
      for (int tt = 0; tt < 4; tt++){
        iacc[tt][0] = (float4v){0.f,0.f,0.f,0.f};
        iacc[tt][1] = iacc[tt][0];
      }
      #pragma unroll
      for (int kc = 0; kc < 4; kc++){
        const long long blo = *(const long long*)(sh_xp8 + kc*32 + q*8);
        const long long bhi = *(const long long*)(sh_xp8 + (kc+4)*32 + q*8);
        #pragma unroll
        for (int tt = 0; tt < 4; tt++){
          iacc[tt][0] = mfma_fp8(ifrag[tt][kc],   blo, iacc[tt][0]);
          iacc[tt][1] = mfma_fp8(ifrag[tt][kc+4], bhi, iacc[tt][1]);
        }
      }
      // overlapped (independent of iou results):
      //  (a) next-column correction partial cp (mask bits j < li of wl_next)
      //  (b) B_tile[li+1] prefetch  (c) xp32[o_upd] prefetch for cou
      if (li < 31){
        const unsigned int wl = wl_next & ((1u << li) - 1u);
        half8v af;
        #pragma unroll
        for (int e = 0; e < 8; e++)
          af[e] = (_Float16)((wl >> (q*8 + e)) & 1u);
        #pragma unroll
        for (int g = 0; g < 2; g++){
          const int fg = f0 + 16*g + r;
          const half8v bf = *(const half8v*)(smem + OFF_DT + fg*80 + q*16);
          float4v ag = (float4v){0.f,0.f,0.f,0.f};
          ag = mfma_f16(af, bf, ag);
          cp[g] = ag[0];
          btn[g] = *(const float*)(smem + (li+1)*1040 + fg*4);
        }
      }
      xpv_pre = sh_xp32[o_upd];
      // gate: select this lane's output, one sigmoid
      float d1 = 0.f;
      #pragma unroll
      for (int tt = 0; tt < 4; tt++) if ((r>>2) == tt){
        #pragma unroll
        for (int jj = 0; jj < 4; jj++) if ((r&3) == jj)
          d1 = iacc[tt][0][jj] + iacc[tt][1][jj];
      }
      const float g1 = d1*vi1 + oxi + bi1;
      const float sg = 1.f / (1.f + __expf(-g1));
      if (wave < 4) sh_p8[o1] = enc8(sg * sh_xp32[o1] * 16.f);  // r-gates
      else          sh_z[o1 - 256] = sg;                        // z-gates
    }
    RAW_BAR();                                          // B3 (p8/z cross-wave)

    // ---- cou matvec: 16 fp8 MFMAs as 4 chains of 4 + fused update ----
    {
      float4v cacc[2][2];
      #pragma unroll
      for (int tt = 0; tt < 2; tt++){
        cacc[tt][0] = (float4v){0.f,0.f,0.f,0.f};
        cacc[tt][1] = cacc[tt][0];
      }
      #pragma unroll
      for (int kc = 0; kc < 4; kc++){
        const long long blo = *(const long long*)(sh_p8 + kc*32 + q*8);
        const long long bhi = *(const long long*)(sh_p8 + (kc+4)*32 + q*8);
        #pragma unroll
        for (int tt = 0; tt < 2; tt++){
          cacc[tt][0] = mfma_fp8(cfrag[tt][kc],   blo, cacc[tt][0]);
          cacc[tt][1] = mfma_fp8(cfrag[tt][kc+4], bhi, cacc[tt][1]);
        }
      }
      if (r < 8){
        float cd = 0.f;
        #pragma unroll
        for (int tt = 0; tt < 2; tt++) if ((r>>2) == tt){
          #pragma unroll
          for (int jj = 0; jj < 4; jj++) if ((r&3) == jj)
            cd = cacc[tt][0][jj] + cacc[tt][1][jj];
        }
        const float v   = cd*invc_l + oxc + bcou_l;
        const float hcv = tanhf(v);
        const float z   = sh_z[o_upd];
        const float hn  = z*xpv_pre + (1.f - z)*hcv;
        pmax = fmaxf(pmax, hn);
        *(_Float16*)(smem + OFF_DT + o_upd*80 + li*2) = (_Float16)(hn - he);
      }
    }
    wl_cur = wl_next;
    // no end barrier: dT consumed same-wave; xp/p8/z fenced by B2/B3
  }

  // ---- epilogue: pooled max -> fc ----
  if (r < 8) sh_pm[o_upd] = pmax;
  __syncthreads();
  if (t < 128){
    const int c = t >> 6;   // 0 or 1
    float s = 0.f;
    #pragma unroll
    for (int qq = 0; qq < 4; qq++){
      const int f = (t & 63) + qq*64;
      s += fc_W[c*256 + f] * sh_pm[f];
    }
    #pragma unroll
    for (int off = 32; off > 0; off >>= 1) s += __shfl_xor(s, off, 64);
    if ((t & 63) == 0) out[b*2 + c] = s + fc_b[c];
  }
}

// ---------------------------------------------------------------------------
extern "C" void kernel_launch(void* const* d_in, const int* in_sizes, int n_in,
                              void* d_out, int out_size, void* d_ws, size_t ws_size,
                              hipStream_t stream)
{
  (void)in_sizes; (void)n_in; (void)out_size; (void)ws_size;
  const float* h      = (const float*)d_in[0];
  const float* adj    = (const float*)d_in[1];
  const float* emb_W  = (const float*)d_in[2];
  const float* ioux_W = (const float*)d_in[3];
  const float* ioux_b = (const float*)d_in[4];
  const float* iouh_W = (const float*)d_in[5];
  const float* iouh_b = (const float*)d_in[6];
  const float* coux_W = (const float*)d_in[7];
  const float* coux_b = (const float*)d_in[8];
  const float* couh_W = (const float*)d_in[9];
  const float* couh_b = (const float*)d_in[10];
  const float* fc_W   = (const float*)d_in[11];
  const float* fc_b   = (const float*)d_in[12];
  float* out = (float*)d_out;

  // ---- carve workspace (256B aligned chunks) ----
  size_t off = 0;
  char* base = (char*)d_ws;
  auto carve = [&](size_t bytes)->char* {
    off = (off + 255) & ~(size_t)255;
    char* p = base + off;
    off += bytes;
    return p;
  };
  _Float16* embW16 = (_Float16*)carve((size_t)256*768*2);
  _Float16* Wcat16 = (_Float16*)carve((size_t)768*256*2);
  float*    biascat= (float*)  carve((size_t)768*4);
  unsigned char* iouh8 = (unsigned char*)carve(131072);
  unsigned char* couh8 = (unsigned char*)carve(65536);
  float*    invrs_iou = (float*)carve(512*4);
  float*    invrs_cou = (float*)carve(256*4);
  float*    dinv   = (float*)  carve((size_t)NB*NN*4);
  unsigned int* maskw = (unsigned int*)carve((size_t)NB*NN*8*4 + 64); // +pad
  _Float16* Hc     = (_Float16*)carve((size_t)NB*NN*FOUT*2);       // h_e
  _Float16* HcT    = (_Float16*)carve((size_t)NB*NN*FOUT*2);       // h_e^T
  _Float16* OUTX   = (_Float16*)carve((size_t)NB*NN*768*2);        // [iou_x;cou_x]

  // raise dynamic LDS cap for the scan kernel (idempotent, non-stream op)
  hipFuncSetAttribute((const void*)scan_kernel,
                      hipFuncAttributeMaxDynamicSharedMemorySize, SCAN_LDS);

  // 1) f16 weight conversion for x-side GEMMs
  prep_kernel<<<dim3(1539), dim3(256), 0, stream>>>(
      emb_W, ioux_W, ioux_b, coux_W, coux_b, embW16, Wcat16, biascat);

  // 2) fp8 quantization of recurrent weights (swizzled for MFMA frags)
  quant_kernel<<<dim3(768), dim3(256), 0, stream>>>(
      iouh_W, couh_W, iouh8, couh8, invrs_iou, invrs_cou);

  // 3) degrees + adjacency column bitmasks (row-read + LDS bit transpose)
  degmask_kernel<<<dim3(NB), dim3(256), 0, stream>>>(adj, maskw, dinv);

  // 4) h_e = h @ emb_W^T
  gemm16_kernel<1><<<dim3(256, 4), dim3(256), 0, stream>>>(
      (const void*)h, embW16, Hc, nullptr, NB*NN, FOUT, FIN, FOUT);

  // 4b) HcT = transpose(Hc) per batch (feeds scan's Hreg init)
  transp_kernel<<<dim3(NB, 8), dim3(256), 0, stream>>>(Hc, HcT);

  // 5) [iou_x ; cou_x] = h_e @ Wcat^T + biascat
  gemm16_kernel<0><<<dim3(256, 12), dim3(256), 0, stream>>>(
      (const void*)Hc, Wcat16, OUTX, biascat, NB*NN, 768, FOUT, 768);

  // 6) sequential tree scan: short-chain restructure
  scan_kernel<<<dim3(NB), dim3(512), SCAN_LDS, stream>>>(
      Hc, HcT, OUTX, iouh8, couh8, invrs_iou, invrs_cou, dinv, maskw,
      iouh_b, couh_b, fc_W, fc_b, out);
}

// Round 10
// 625.894 us; speedup vs baseline: 1.1977x; 1.1977x over previous
//
#include <hip/hip_runtime.h>
#include <hip/hip_fp16.h>

// Problem constants: B=64, N=256, F_IN=768, F_OUT=256
#define NB    64
#define NN    256
#define FIN   768
#define FOUT  256

typedef _Float16 half8v __attribute__((ext_vector_type(8)));
typedef float    float4v __attribute__((ext_vector_type(4)));

// f32 -> fp8 e4m3 (OCP, RNE) single value
__device__ inline unsigned char enc8(float v){
#if __has_builtin(__builtin_amdgcn_cvt_pk_fp8_f32)
  return (unsigned char)(__builtin_amdgcn_cvt_pk_fp8_f32(v, v, 0, false) & 0xFF);
#else
  float best = 1e30f; unsigned char bc = 0;
  for (int c = 0; c < 256; c++){
    if ((c & 0x7F) == 0x7F) continue;            // NaN codes
    int e = (c >> 3) & 15, mnt = c & 7;
    float mag = e ? ldexpf(1.f + mnt*0.125f, e-7) : ldexpf(mnt*0.125f, -6);
    float d = (c >> 7) ? -mag : mag;
    float err = fabsf(v - d);
    if (err < best){ best = err; bc = (unsigned char)c; }
  }
  return bc;
#endif
}

__device__ inline float4v mfma_fp8(long long a, long long b, float4v c){
  return __builtin_amdgcn_mfma_f32_16x16x32_fp8_fp8(a, b, c, 0, 0, 0);
}
__device__ inline float4v mfma_f16(half8v a, half8v b, float4v c){
  return __builtin_amdgcn_mfma_f32_16x16x32_f16(a, b, c, 0, 0, 0);
}

// ---------------------------------------------------------------------------
// setup: fused prep + quant + degmask (mutually independent; blockIdx roles).
//   blocks [0,1539): prep f16 conversions
//   blocks [1539,2307): quant fp8 rows (row = bid-1539)
//   blocks [2307,2371): degmask (b = bid-2307)
// ---------------------------------------------------------------------------
__global__ __launch_bounds__(256) void setup_kernel(
    const float* __restrict__ emb_W, const float* __restrict__ ioux_W,
    const float* __restrict__ ioux_b, const float* __restrict__ coux_W,
    const float* __restrict__ coux_b,
    const float* __restrict__ iouh_W, const float* __restrict__ couh_W,
    const float* __restrict__ adj,
    _Float16* __restrict__ embW16, _Float16* __restrict__ Wcat16,
    float* __restrict__ biascat,
    unsigned char* __restrict__ iouh8, unsigned char* __restrict__ couh8,
    float* __restrict__ invrs_iou, float* __restrict__ invrs_cou,
    unsigned int* __restrict__ maskw, float* __restrict__ dinv)
{
  __shared__ float sm[256];               // quant reduction
  __shared__ unsigned int rb[256][8];     // degmask bit-transpose
  const int bid = blockIdx.x;
  const int t   = threadIdx.x;

  if (bid < 1539){
    // ---- prep role ----
    int idx = bid*256 + t;
    if (idx < 196608) { embW16[idx] = (_Float16)emb_W[idx]; return; }
    idx -= 196608;
    if (idx < 196608) {
      int o = idx >> 8, k = idx & 255;
      float v = (o < 512) ? ioux_W[o*256 + k] : coux_W[(o-512)*256 + k];
      Wcat16[idx] = (_Float16)v; return;
    }
    idx -= 196608;
    if (idx < 768) biascat[idx] = (idx < 512) ? ioux_b[idx] : coux_b[idx-512];
    return;
  }

  if (bid < 2307){
    // ---- quant role ----
    const int row = bid - 1539;           // 0..767
    const bool is_iou = (row < 512);
    const int rl = is_iou ? row : row - 512;
    const float w = is_iou ? iouh_W[(size_t)rl*256 + t] : couh_W[(size_t)rl*256 + t];
    sm[t] = fabsf(w);
    __syncthreads();
    for (int s = 128; s > 0; s >>= 1){
      if (t < s) sm[t] = fmaxf(sm[t], sm[t+s]);
      __syncthreads();
    }
    const float mx = sm[0];
    const float rs = (mx > 1e-20f) ? (240.0f / mx) : 1.0f;
    const unsigned char byte = enc8(w * rs);
    const int off = ((rl>>4)*8 + (t>>5))*512 + ((t>>3)&3)*128 + (rl&15)*8 + (t&7);
    if (is_iou) iouh8[off] = byte; else couh8[off] = byte;
    if (t == 0){
      const float inv = 1.0f / (rs * 16.0f);
      if (is_iou) invrs_iou[rl] = inv; else invrs_cou[rl] = inv;
    }
    return;
  }

  // ---- degmask role: one row-major read + LDS bit transpose ----
  {
    const int b = bid - 2307;
    const float* rowp = adj + (size_t)b*NN*NN + (size_t)t*NN;
    float s = 0.f;
    #pragma unroll
    for (int qc = 0; qc < 8; qc++){
      unsigned int w = 0;
      const float4* rp = (const float4*)(rowp + qc*32);
      #pragma unroll
      for (int j4 = 0; j4 < 8; j4++){
        float4 v = rp[j4];
        s += v.x + v.y + v.z + v.w;
        const int sh = j4*4;
        w |= (v.x != 0.f ? 1u : 0u) << sh;
        w |= (v.y != 0.f ? 1u : 0u) << (sh+1);
        w |= (v.z != 0.f ? 1u : 0u) << (sh+2);
        w |= (v.w != 0.f ? 1u : 0u) << (sh+3);
      }
      rb[t][qc] = w;
    }
    dinv[b*NN + t] = (s != 0.f) ? 1.0f/s : 0.0f;
    __syncthreads();
    #pragma unroll
    for (int qc = 0; qc < 8; qc++){
      unsigned int w = 0;
      #pragma unroll
      for (int jj = 0; jj < 32; jj++)
        w |= ((rb[qc*32 + jj][t>>5] >> (t&31)) & 1u) << jj;
      maskw[((size_t)b*NN + t)*8 + qc] = w;
    }
  }
}

// ---------------------------------------------------------------------------
// GEMM (unchanged, validated): C = A @ Bw^T (+bias), C f16. Used for gemm4.
// ---------------------------------------------------------------------------
template<int AF32>
__global__ __launch_bounds__(256) void gemm16_kernel(
    const void* __restrict__ Aq, const _Float16* __restrict__ Bw,
    _Float16* __restrict__ Cout, const float* __restrict__ bias,
    int M, int N, int K, int ldc)
{
  const int wave = threadIdx.x >> 6;
  const int lane = threadIdx.x & 63;
  const int m0 = (blockIdx.x*4 + wave)*16;
  const int n0 = blockIdx.y*64;
  const int mrow = m0 + (lane & 15);
  const int kgrp = lane >> 4;
  float4v acc[4];
  #pragma unroll
  for (int nt = 0; nt < 4; nt++) acc[nt] = (float4v){0.f,0.f,0.f,0.f};

  for (int k0 = 0; k0 < K; k0 += 32){
    const int ka = k0 + kgrp*8;
    half8v af;
    if (AF32){
      const float* A = (const float*)Aq;
      const float4* ap = (const float4*)(A + (size_t)mrow*K + ka);
      float4 a0 = ap[0], a1 = ap[1];
      af[0]=(_Float16)a0.x; af[1]=(_Float16)a0.y; af[2]=(_Float16)a0.z; af[3]=(_Float16)a0.w;
      af[4]=(_Float16)a1.x; af[5]=(_Float16)a1.y; af[6]=(_Float16)a1.z; af[7]=(_Float16)a1.w;
    } else {
      const _Float16* A = (const _Float16*)Aq;
      af = *(const half8v*)(A + (size_t)mrow*K + ka);
    }
    #pragma unroll
    for (int nt = 0; nt < 4; nt++){
      const int ncol = n0 + nt*16 + (lane & 15);
      half8v bf = *(const half8v*)(Bw + (size_t)ncol*K + ka);
      acc[nt] = __builtin_amdgcn_mfma_f32_16x16x32_f16(af, bf, acc[nt], 0, 0, 0);
    }
  }
  #pragma unroll
  for (int nt = 0; nt < 4; nt++){
    const int ncol = n0 + nt*16 + (lane & 15);
    const float bv = bias ? bias[ncol] : 0.f;
    #pragma unroll
    for (int r = 0; r < 4; r++){
      const int orow = m0 + (lane>>4)*4 + r;
      Cout[(size_t)orow*ldc + ncol] = (_Float16)(acc[nt][r] + bv);
    }
  }
}

// ---------------------------------------------------------------------------
// tail: fused gemm5 (OUTX = Hc @ Wcat^T + biascat) + transp (HcT).
// Both depend only on Hc; disjoint outputs. blockIdx roles:
//   [0,3072): gemm  (bx = bid&255, by = bid>>8, 12 col-groups)
//   [3072,3584): transp (b = idx&63, fg = idx>>6)
// ---------------------------------------------------------------------------
__global__ __launch_bounds__(256) void tail_kernel(
    const _Float16* __restrict__ Hc, const _Float16* __restrict__ Wcat16,
    const float* __restrict__ biascat,
    _Float16* __restrict__ OUTX, _Float16* __restrict__ HcT)
{
  __shared__ _Float16 tile[32][264];
  const int bid = blockIdx.x;
  const int t   = threadIdx.x;

  if (bid < 3072){
    // ---- gemm role: M=16384, N=768, K=256, ldc=768 ----
    const int bx = bid & 255, by = bid >> 8;
    const int wave = t >> 6;
    const int lane = t & 63;
    const int m0 = (bx*4 + wave)*16;
    const int n0 = by*64;
    const int mrow = m0 + (lane & 15);
    const int kgrp = lane >> 4;
    float4v acc[4];
    #pragma unroll
    for (int nt = 0; nt < 4; nt++) acc[nt] = (float4v){0.f,0.f,0.f,0.f};
    for (int k0 = 0; k0 < 256; k0 += 32){
      const int ka = k0 + kgrp*8;
      const half8v af = *(const half8v*)(Hc + (size_t)mrow*256 + ka);
      #pragma unroll
      for (int nt = 0; nt < 4; nt++){
        const int ncol = n0 + nt*16 + (lane & 15);
        half8v bf = *(const half8v*)(Wcat16 + (size_t)ncol*256 + ka);
        acc[nt] = __builtin_amdgcn_mfma_f32_16x16x32_f16(af, bf, acc[nt], 0, 0, 0);
      }
    }
    #pragma unroll
    for (int nt = 0; nt < 4; nt++){
      const int ncol = n0 + nt*16 + (lane & 15);
      const float bv = biascat[ncol];
      #pragma unroll
      for (int r = 0; r < 4; r++){
        const int orow = m0 + (lane>>4)*4 + r;
        OUTX[(size_t)orow*768 + ncol] = (_Float16)(acc[nt][r] + bv);
      }
    }
    return;
  }

  // ---- transp role ----
  {
    const int idx = bid - 3072;
    const int b = idx & 63, fg = idx >> 6;   // fg: feature group of 32
    #pragma unroll
    for (int pass = 0; pass < 4; pass++){
      const int n  = pass*64 + (t>>2);
      const int f8 = (t&3)*8;
      const half8v v = *(const half8v*)(Hc + (size_t)(b*NN + n)*FOUT + fg*32 + f8);
      #pragma unroll
      for (int e = 0; e < 8; e++) tile[f8+e][n] = v[e];
    }
    __syncthreads();
    const int f = t>>3, ch = t&7;
    _Float16* dst = HcT + ((size_t)b*FOUT + fg*32 + f)*NN + ch*32;
    #pragma unroll
    for (int k = 0; k < 4; k++)
      *(half8v*)(dst + k*8) = *(const half8v*)(&tile[f][ch*32 + k*8]);
  }
}

// ---------------------------------------------------------------------------
// scan R14 (reverted verbatim — best measured: 390 µs). 8 waves (512 thr),
// launch_bounds(512,2); weights+H^T in regs (no spill at VGPR=120);
// 2 __syncthreads/iter (xp@B2, p8/z@B3 — the only cross-wave edges);
// boundary GEMM barrier-free (same-wave dataflow).
// R15 (raw-bar+prefetch, 406) and R16 (split-K+pipeline, 500 w/ spills)
// both regressed — this structure is the proven local optimum.
// LDS map (dynamic, 87040 B).
// ---------------------------------------------------------------------------
#define OFF_BT   0
#define OFF_DT   33280
#define OFF_HNT  53760
#define OFF_XP32 74240
#define OFF_XP8  75264
#define OFF_P8   75520
#define OFF_Z    75776
#define OFF_PM   76800
#define OFF_MASK 77824
#define OFF_DINV 86016
#define SCAN_LDS 87040

__global__ __launch_bounds__(512, 2)
void scan_kernel(
    const _Float16* __restrict__ Hc,    // [B*N][256] f16 = h_e (row-major)
    const _Float16* __restrict__ HcT,   // [B][256 feat][256 node] f16
    const _Float16* __restrict__ OUTX,  // [B*N][768] f16: [iou_x ; cou_x]
    const unsigned char* __restrict__ iouh8,  // swizzled fp8 [512][256]
    const unsigned char* __restrict__ couh8,  // swizzled fp8 [256][256]
    const float* __restrict__ invrs_iou,      // [512]
    const float* __restrict__ invrs_cou,      // [256]
    const float* __restrict__ dinv,     // [B*N]
    const unsigned int* __restrict__ maskw, // [B*N][8]
    const float* __restrict__ iouh_b,   // [512]
    const float* __restrict__ couh_b,   // [256]
    const float* __restrict__ fc_W,     // [2][256]
    const float* __restrict__ fc_b,     // [2]
    float* __restrict__ out)            // [B][2]
{
  const int b    = blockIdx.x;
  const int t    = threadIdx.x;        // 0..511
  const int wave = t >> 6;             // 0..7
  const int lane = t & 63;
  const int q    = lane >> 4;          // k-octet within MFMA frags
  const int r    = lane & 15;          // row/col index within MFMA tile
  const int f0   = 32*wave;            // wave's feature-slice base

  extern __shared__ __align__(16) char smem[];
  float*         sh_xp32 = (float*)(smem + OFF_XP32);
  unsigned char* sh_xp8  = (unsigned char*)(smem + OFF_XP8);
  unsigned char* sh_p8   = (unsigned char*)(smem + OFF_P8);
  float*         sh_z    = (float*)(smem + OFF_Z);
  float*         sh_pm   = (float*)(smem + OFF_PM);
  unsigned int*  sh_mask = (unsigned int*)(smem + OFF_MASK);
  float*         sh_dinv = (float*)(smem + OFF_DINV);

  // ---- one-time staging: zero delta-tile (5120 dw), mask words, dinv ----
  #pragma unroll
  for (int k = 0; k < 10; k++)
    ((unsigned int*)(smem + OFF_DT))[k*512 + t] = 0u;
  {
    const unsigned int* mg = maskw + ((size_t)b*NN)*8;
    #pragma unroll
    for (int k = 0; k < 4; k++) sh_mask[k*512 + t] = mg[k*512 + t];
    if (t < 256) sh_dinv[t] = dinv[(size_t)b*NN + t];
  }

  // ---- Hreg[g][ks]: H^T[f0+16g+r][ks*32 + q*8 + e] (64 VGPR) ----
  half8v Hreg[2][8];
  #pragma unroll
  for (int g = 0; g < 2; g++){
    const _Float16* hp = HcT + ((size_t)b*FOUT + f0 + 16*g + r)*NN + q*8;
    #pragma unroll
    for (int ks = 0; ks < 8; ks++)
      Hreg[g][ks] = *(const half8v*)(hp + ks*32);
  }

  // ---- recurrent weight frags (loop-invariant; 64+32 VGPR) ----
  long long ifrag[4][8];
  #pragma unroll
  for (int tt = 0; tt < 4; tt++)
    #pragma unroll
    for (int kc = 0; kc < 8; kc++)
      ifrag[tt][kc] = *(const long long*)(iouh8 + (size_t)(((4*wave+tt)*8 + kc)*512) + q*128 + r*8);
  long long cfrag[2][8];
  #pragma unroll
  for (int tt = 0; tt < 2; tt++)
    #pragma unroll
    for (int kc = 0; kc < 8; kc++)
      cfrag[tt][kc] = *(const long long*)(couh8 + (size_t)(((2*wave+tt)*8 + kc)*512) + q*128 + r*8);

  // ---- per-lane output assignments ----
  const int o1    = 64*wave + 16*(r>>2) + q*4 + (r&3);       // iou: 1/lane
  const int o_upd = 32*wave + 16*((r>>2)&1) + q*4 + (r&3);   // cou: lanes r<8
  const float bi1 = iouh_b[o1];
  const float vi1 = invrs_iou[o1];
  const float bcou_l = couh_b[o_upd];
  const float invc_l = invrs_cou[o_upd];
  float pmax = -1e30f;

  __syncthreads();   // staging done
  unsigned int wl_cur = sh_mask[0];

  #pragma unroll 1
  for (int i = 0; i < NN; i++){
    const size_t row = (size_t)b*NN + i;

    // ======== tile boundary (no barrier: all edges same-wave) ========
    if ((i & 31) == 0){
      const int tile = i >> 5;
      if (tile > 0){
        const int tprev = tile - 1;
        #pragma unroll
        for (int g = 0; g < 2; g++){
          const half8v hv = *(const half8v*)(smem + OFF_HNT + (f0 + 16*g + r)*80 + q*16);
          #pragma unroll
          for (int ks = 0; ks < 8; ks++) if (ks == tprev) Hreg[g][ks] = hv;
        }
      }
      float4v bacc[2][2];
      #pragma unroll
      for (int rt = 0; rt < 2; rt++)
        #pragma unroll
        for (int g = 0; g < 2; g++) bacc[rt][g] = (float4v){0.f,0.f,0.f,0.f};
      #pragma unroll
      for (int rt = 0; rt < 2; rt++){
        #pragma unroll
        for (int ks = 0; ks < 8; ks++){
          const unsigned int wm = sh_mask[(i + rt*16 + r)*8 + ks];
          half8v am;
          #pragma unroll
          for (int e = 0; e < 8; e++)
            am[e] = (_Float16)((wm >> (q*8 + e)) & 1u);
          bacc[rt][0] = mfma_f16(am, Hreg[0][ks], bacc[rt][0]);
          bacc[rt][1] = mfma_f16(am, Hreg[1][ks], bacc[rt][1]);
        }
      }
      #pragma unroll
      for (int rt = 0; rt < 2; rt++)
        #pragma unroll
        for (int g = 0; g < 2; g++)
          #pragma unroll
          for (int jj = 0; jj < 4; jj++)
            *(float*)(smem + (rt*16 + q*4 + jj)*1040 + (f0 + 16*g + r)*4) = bacc[rt][g][jj];
    }
    // ================================================================

    const int li = i & 31;
    const unsigned int wl_next = sh_mask[((i+1)&255)*8 + (((i+1)>>5)&7)];
    const float oxi = (float)OUTX[row*768 + o1];
    const float oxc = (float)OUTX[row*768 + 512 + o_upd];
    const float he  = (float)Hc[row*FOUT + o_upd];
    const float dv  = sh_dinv[i];

    // ---- agg: 2 K=32 correction MFMAs + B_tile (all same-wave inputs) ----
    {
      const unsigned int wl = wl_cur & ((1u << li) - 1u);  // li==0 -> 0
      half8v af;
      #pragma unroll
      for (int e = 0; e < 8; e++)
        af[e] = (_Float16)((wl >> (q*8 + e)) & 1u);
      #pragma unroll
      for (int g = 0; g < 2; g++){
        const int fg = f0 + 16*g + r;
        const half8v bf = *(const half8v*)(smem + OFF_DT + fg*80 + q*16);
        float4v ag = (float4v){0.f,0.f,0.f,0.f};
        ag = mfma_f16(af, bf, ag);
        const float bt = *(const float*)(smem + li*1040 + fg*4);
        const float xp = (bt + ag[0]) * dv;
        if (q == 0)      sh_xp32[fg] = xp;
        else if (q == 1) sh_xp8[fg] = enc8(xp * 16.f);
      }
    }
    wl_cur = wl_next;
    __syncthreads();                                    // B2 (xp cross-wave)

    // ---- iou matvec: 32 fp8 MFMAs, 1 sigmoid/lane ----
    {
      float4v iacc[4];
      #pragma unroll
      for (int tt = 0; tt < 4; tt++) iacc[tt] = (float4v){0.f,0.f,0.f,0.f};
      #pragma unroll
      for (int kc = 0; kc < 8; kc++){
        const long long bfr = *(const long long*)(sh_xp8 + kc*32 + q*8);
        #pragma unroll
        for (int tt = 0; tt < 4; tt++)
          iacc[tt] = mfma_fp8(ifrag[tt][kc], bfr, iacc[tt]);
      }
      float d1 = 0.f;
      #pragma unroll
      for (int tt = 0; tt < 4; tt++) if ((r>>2) == tt){
        #pragma unroll
        for (int jj = 0; jj < 4; jj++) if ((r&3) == jj) d1 = iacc[tt][jj];
      }
      const float g1 = d1*vi1 + oxi + bi1;
      const float sg = 1.f / (1.f + __expf(-g1));
      if (wave < 4) sh_p8[o1] = enc8(sg * sh_xp32[o1] * 16.f);  // r-gates
      else          sh_z[o1 - 256] = sg;                        // z-gates
    }
    __syncthreads();                                    // B3 (p8/z cross-wave)

    // ---- cou matvec: 16 fp8 MFMAs + fused update (lanes r<8) ----
    {
      float4v cacc[2];
      cacc[0] = (float4v){0.f,0.f,0.f,0.f};
      cacc[1] = cacc[0];
      #pragma unroll
      for (int kc = 0; kc < 8; kc++){
        const long long bfr = *(const long long*)(sh_p8 + kc*32 + q*8);
        cacc[0] = mfma_fp8(cfrag[0][kc], bfr, cacc[0]);
        cacc[1] = mfma_fp8(cfrag[1][kc], bfr, cacc[1]);
      }
      if (r < 8){
        float cd = 0.f;
        #pragma unroll
        for (int tt = 0; tt < 2; tt++) if ((r>>2) == tt){
          #pragma unroll
          for (int jj = 0; jj < 4; jj++) if ((r&3) == jj) cd = cacc[tt][jj];
        }
        const float v   = cd*invc_l + oxc + bcou_l;
        const float hcv = tanhf(v);
        const float z   = sh_z[o_upd];
        const float xpv = sh_xp32[o_upd];
        const float hn  = z*xpv + (1.f - z)*hcv;
        pmax = fmaxf(pmax, hn);
        *(_Float16*)(smem + OFF_DT  + o_upd*80 + li*2) = (_Float16)(hn - he);
        *(_Float16*)(smem + OFF_HNT + o_upd*80 + li*2) = (_Float16)hn;
      }
    }
    // no B4: dT/hnT consumed same-wave; xp/p8/z overwrites fenced by B2/B3
  }

  // ---- epilogue: pooled max -> fc ----
  if (r < 8) sh_pm[o_upd] = pmax;
  __syncthreads();
  if (t < 128){
    const int c = t >> 6;   // 0 or 1
    float s = 0.f;
    #pragma unroll
    for (int qq = 0; qq < 4; qq++){
      const int f = (t & 63) + qq*64;
      s += fc_W[c*256 + f] * sh_pm[f];
    }
    #pragma unroll
    for (int off = 32; off > 0; off >>= 1) s += __shfl_xor(s, off, 64);
    if ((t & 63) == 0) out[b*2 + c] = s + fc_b[c];
  }
}

// ---------------------------------------------------------------------------
extern "C" void kernel_launch(void* const* d_in, const int* in_sizes, int n_in,
                              void* d_out, int out_size, void* d_ws, size_t ws_size,
                              hipStream_t stream)
{
  (void)in_sizes; (void)n_in; (void)out_size; (void)ws_size;
  const float* h      = (const float*)d_in[0];
  const float* adj    = (const float*)d_in[1];
  const float* emb_W  = (const float*)d_in[2];
  const float* ioux_W = (const float*)d_in[3];
  const float* ioux_b = (const float*)d_in[4];
  const float* iouh_W = (const float*)d_in[5];
  const float* iouh_b = (const float*)d_in[6];
  const float* coux_W = (const float*)d_in[7];
  const float* coux_b = (const float*)d_in[8];
  const float* couh_W = (const float*)d_in[9];
  const float* couh_b = (const float*)d_in[10];
  const float* fc_W   = (const float*)d_in[11];
  const float* fc_b   = (const float*)d_in[12];
  float* out = (float*)d_out;

  // ---- carve workspace (256B aligned chunks) ----
  size_t off = 0;
  char* base = (char*)d_ws;
  auto carve = [&](size_t bytes)->char* {
    off = (off + 255) & ~(size_t)255;
    char* p = base + off;
    off += bytes;
    return p;
  };
  _Float16* embW16 = (_Float16*)carve((size_t)256*768*2);
  _Float16* Wcat16 = (_Float16*)carve((size_t)768*256*2);
  float*    biascat= (float*)  carve((size_t)768*4);
  unsigned char* iouh8 = (unsigned char*)carve(131072);
  unsigned char* couh8 = (unsigned char*)carve(65536);
  float*    invrs_iou = (float*)carve(512*4);
  float*    invrs_cou = (float*)carve(256*4);
  float*    dinv   = (float*)  carve((size_t)NB*NN*4);
  unsigned int* maskw = (unsigned int*)carve((size_t)NB*NN*8*4 + 64); // +pad
  _Float16* Hc     = (_Float16*)carve((size_t)NB*NN*FOUT*2);       // h_e
  _Float16* HcT    = (_Float16*)carve((size_t)NB*NN*FOUT*2);       // h_e^T
  _Float16* OUTX   = (_Float16*)carve((size_t)NB*NN*768*2);        // [iou_x;cou_x]

  // raise dynamic LDS cap for the scan kernel (idempotent, non-stream op)
  hipFuncSetAttribute((const void*)scan_kernel,
                      hipFuncAttributeMaxDynamicSharedMemorySize, SCAN_LDS);

  // 1) fused setup: prep + quant + degmask (independent, one launch)
  setup_kernel<<<dim3(2371), dim3(256), 0, stream>>>(
      emb_W, ioux_W, ioux_b, coux_W, coux_b, iouh_W, couh_W, adj,
      embW16, Wcat16, biascat, iouh8, couh8, invrs_iou, invrs_cou,
      maskw, dinv);

  // 2) h_e = h @ emb_W^T
  gemm16_kernel<1><<<dim3(256, 4), dim3(256), 0, stream>>>(
      (const void*)h, embW16, Hc, nullptr, NB*NN, FOUT, FIN, FOUT);

  // 3) fused tail: OUTX GEMM + HcT transpose (both read only Hc)
  tail_kernel<<<dim3(3584), dim3(256), 0, stream>>>(
      Hc, Wcat16, biascat, OUTX, HcT);

  // 4) sequential tree scan (R14 structure, proven 390 us)
  scan_kernel<<<dim3(NB), dim3(512), SCAN_LDS, stream>>>(
      Hc, HcT, OUTX, iouh8, couh8, invrs_iou, invrs_cou, dinv, maskw,
      iouh_b, couh_b, fc_W, fc_b, out);
}

// Round 11
// 616.246 us; speedup vs baseline: 1.2165x; 1.0157x over previous
//
#include <hip/hip_runtime.h>
#include <hip/hip_fp16.h>

// Problem constants: B=64, N=256, F_IN=768, F_OUT=256
#define NB    64
#define NN    256
#define FIN   768
#define FOUT  256

typedef _Float16 half8v __attribute__((ext_vector_type(8)));
typedef float    float4v __attribute__((ext_vector_type(4)));

// f32 -> fp8 e4m3 (OCP, RNE) single value
__device__ inline unsigned char enc8(float v){
#if __has_builtin(__builtin_amdgcn_cvt_pk_fp8_f32)
  return (unsigned char)(__builtin_amdgcn_cvt_pk_fp8_f32(v, v, 0, false) & 0xFF);
#else
  float best = 1e30f; unsigned char bc = 0;
  for (int c = 0; c < 256; c++){
    if ((c & 0x7F) == 0x7F) continue;            // NaN codes
    int e = (c >> 3) & 15, mnt = c & 7;
    float mag = e ? ldexpf(1.f + mnt*0.125f, e-7) : ldexpf(mnt*0.125f, -6);
    float d = (c >> 7) ? -mag : mag;
    float err = fabsf(v - d);
    if (err < best){ best = err; bc = (unsigned char)c; }
  }
  return bc;
#endif
}

__device__ inline float4v mfma_fp8(long long a, long long b, float4v c){
  return __builtin_amdgcn_mfma_f32_16x16x32_fp8_fp8(a, b, c, 0, 0, 0);
}
__device__ inline float4v mfma_f16(half8v a, half8v b, float4v c){
  return __builtin_amdgcn_mfma_f32_16x16x32_f16(a, b, c, 0, 0, 0);
}

// ---------------------------------------------------------------------------
// setup: fused prep + quant + degmask (mutually independent; blockIdx roles).
// ---------------------------------------------------------------------------
__global__ __launch_bounds__(256) void setup_kernel(
    const float* __restrict__ emb_W, const float* __restrict__ ioux_W,
    const float* __restrict__ ioux_b, const float* __restrict__ coux_W,
    const float* __restrict__ coux_b,
    const float* __restrict__ iouh_W, const float* __restrict__ couh_W,
    const float* __restrict__ adj,
    _Float16* __restrict__ embW16, _Float16* __restrict__ Wcat16,
    float* __restrict__ biascat,
    unsigned char* __restrict__ iouh8, unsigned char* __restrict__ couh8,
    float* __restrict__ invrs_iou, float* __restrict__ invrs_cou,
    unsigned int* __restrict__ maskw, float* __restrict__ dinv)
{
  __shared__ float sm[256];               // quant reduction
  __shared__ unsigned int rb[256][8];     // degmask bit-transpose
  const int bid = blockIdx.x;
  const int t   = threadIdx.x;

  if (bid < 1539){
    // ---- prep role ----
    int idx = bid*256 + t;
    if (idx < 196608) { embW16[idx] = (_Float16)emb_W[idx]; return; }
    idx -= 196608;
    if (idx < 196608) {
      int o = idx >> 8, k = idx & 255;
      float v = (o < 512) ? ioux_W[o*256 + k] : coux_W[(o-512)*256 + k];
      Wcat16[idx] = (_Float16)v; return;
    }
    idx -= 196608;
    if (idx < 768) biascat[idx] = (idx < 512) ? ioux_b[idx] : coux_b[idx-512];
    return;
  }

  if (bid < 2307){
    // ---- quant role ----
    const int row = bid - 1539;           // 0..767
    const bool is_iou = (row < 512);
    const int rl = is_iou ? row : row - 512;
    const float w = is_iou ? iouh_W[(size_t)rl*256 + t] : couh_W[(size_t)rl*256 + t];
    sm[t] = fabsf(w);
    __syncthreads();
    for (int s = 128; s > 0; s >>= 1){
      if (t < s) sm[t] = fmaxf(sm[t], sm[t+s]);
      __syncthreads();
    }
    const float mx = sm[0];
    const float rs = (mx > 1e-20f) ? (240.0f / mx) : 1.0f;
    const unsigned char byte = enc8(w * rs);
    const int off = ((rl>>4)*8 + (t>>5))*512 + ((t>>3)&3)*128 + (rl&15)*8 + (t&7);
    if (is_iou) iouh8[off] = byte; else couh8[off] = byte;
    if (t == 0){
      const float inv = 1.0f / (rs * 16.0f);
      if (is_iou) invrs_iou[rl] = inv; else invrs_cou[rl] = inv;
    }
    return;
  }

  // ---- degmask role: one row-major read + LDS bit transpose ----
  {
    const int b = bid - 2307;
    const float* rowp = adj + (size_t)b*NN*NN + (size_t)t*NN;
    float s = 0.f;
    #pragma unroll
    for (int qc = 0; qc < 8; qc++){
      unsigned int w = 0;
      const float4* rp = (const float4*)(rowp + qc*32);
      #pragma unroll
      for (int j4 = 0; j4 < 8; j4++){
        float4 v = rp[j4];
        s += v.x + v.y + v.z + v.w;
        const int sh = j4*4;
        w |= (v.x != 0.f ? 1u : 0u) << sh;
        w |= (v.y != 0.f ? 1u : 0u) << (sh+1);
        w |= (v.z != 0.f ? 1u : 0u) << (sh+2);
        w |= (v.w != 0.f ? 1u : 0u) << (sh+3);
      }
      rb[t][qc] = w;
    }
    dinv[b*NN + t] = (s != 0.f) ? 1.0f/s : 0.0f;
    __syncthreads();
    #pragma unroll
    for (int qc = 0; qc < 8; qc++){
      unsigned int w = 0;
      #pragma unroll
      for (int jj = 0; jj < 32; jj++)
        w |= ((rb[qc*32 + jj][t>>5] >> (t&31)) & 1u) << jj;
      maskw[((size_t)b*NN + t)*8 + qc] = w;
    }
  }
}

// ---------------------------------------------------------------------------
// GEMM: C = A @ Bw^T (+bias), C f16. NTL = column-tiles (of 16) per block.
// R18: NTL=8 for gemm4 (grid 256x2) -> A (f32 h, 50MB) read 2x not 4x.
// ---------------------------------------------------------------------------
template<int AF32, int NTL>
__global__ __launch_bounds__(256) void gemm16_kernel(
    const void* __restrict__ Aq, const _Float16* __restrict__ Bw,
    _Float16* __restrict__ Cout, const float* __restrict__ bias,
    int M, int N, int K, int ldc)
{
  const int wave = threadIdx.x >> 6;
  const int lane = threadIdx.x & 63;
  const int m0 = (blockIdx.x*4 + wave)*16;
  const int n0 = blockIdx.y*(16*NTL);
  const int mrow = m0 + (lane & 15);
  const int kgrp = lane >> 4;
  float4v acc[NTL];
  #pragma unroll
  for (int nt = 0; nt < NTL; nt++) acc[nt] = (float4v){0.f,0.f,0.f,0.f};

  for (int k0 = 0; k0 < K; k0 += 32){
    const int ka = k0 + kgrp*8;
    half8v af;
    if (AF32){
      const float* A = (const float*)Aq;
      const float4* ap = (const float4*)(A + (size_t)mrow*K + ka);
      float4 a0 = ap[0], a1 = ap[1];
      af[0]=(_Float16)a0.x; af[1]=(_Float16)a0.y; af[2]=(_Float16)a0.z; af[3]=(_Float16)a0.w;
      af[4]=(_Float16)a1.x; af[5]=(_Float16)a1.y; af[6]=(_Float16)a1.z; af[7]=(_Float16)a1.w;
    } else {
      const _Float16* A = (const _Float16*)Aq;
      af = *(const half8v*)(A + (size_t)mrow*K + ka);
    }
    #pragma unroll
    for (int nt = 0; nt < NTL; nt++){
      const int ncol = n0 + nt*16 + (lane & 15);
      half8v bf = *(const half8v*)(Bw + (size_t)ncol*K + ka);
      acc[nt] = __builtin_amdgcn_mfma_f32_16x16x32_f16(af, bf, acc[nt], 0, 0, 0);
    }
  }
  #pragma unroll
  for (int nt = 0; nt < NTL; nt++){
    const int ncol = n0 + nt*16 + (lane & 15);
    const float bv = bias ? bias[ncol] : 0.f;
    #pragma unroll
    for (int r = 0; r < 4; r++){
      const int orow = m0 + (lane>>4)*4 + r;
      Cout[(size_t)orow*ldc + ncol] = (_Float16)(acc[nt][r] + bv);
    }
  }
}

// ---------------------------------------------------------------------------
// tail: fused gemm5 (OUTX = Hc @ Wcat^T + biascat) + transp (HcT).
// R18: gemm role folds 2 col-groups per block (8 tiles, acc[8]) -> Hc
// re-read 6x not 12x. blockIdx roles:
//   [0,1536): gemm (bx = bid&255, seg = bid>>8 in 0..5, 128 cols each)
//   [1536,2048): transp (b = idx&63, fg = idx>>6)
// ---------------------------------------------------------------------------
__global__ __launch_bounds__(256) void tail_kernel(
    const _Float16* __restrict__ Hc, const _Float16* __restrict__ Wcat16,
    const float* __restrict__ biascat,
    _Float16* __restrict__ OUTX, _Float16* __restrict__ HcT)
{
  __shared__ _Float16 tile[32][264];
  const int bid = blockIdx.x;
  const int t   = threadIdx.x;

  if (bid < 1536){
    // ---- gemm role: M=16384, N=768, K=256, ldc=768; 8 col-tiles ----
    const int bx = bid & 255, seg = bid >> 8;
    const int wave = t >> 6;
    const int lane = t & 63;
    const int m0 = (bx*4 + wave)*16;
    const int n0 = seg*128;
    const int mrow = m0 + (lane & 15);
    const int kgrp = lane >> 4;
    float4v acc[8];
    #pragma unroll
    for (int nt = 0; nt < 8; nt++) acc[nt] = (float4v){0.f,0.f,0.f,0.f};
    for (int k0 = 0; k0 < 256; k0 += 32){
      const int ka = k0 + kgrp*8;
      const half8v af = *(const half8v*)(Hc + (size_t)mrow*256 + ka);
      #pragma unroll
      for (int nt = 0; nt < 8; nt++){
        const int ncol = n0 + nt*16 + (lane & 15);
        half8v bf = *(const half8v*)(Wcat16 + (size_t)ncol*256 + ka);
        acc[nt] = __builtin_amdgcn_mfma_f32_16x16x32_f16(af, bf, acc[nt], 0, 0, 0);
      }
    }
    #pragma unroll
    for (int nt = 0; nt < 8; nt++){
      const int ncol = n0 + nt*16 + (lane & 15);
      const float bv = biascat[ncol];
      #pragma unroll
      for (int r = 0; r < 4; r++){
        const int orow = m0 + (lane>>4)*4 + r;
        OUTX[(size_t)orow*768 + ncol] = (_Float16)(acc[nt][r] + bv);
      }
    }
    return;
  }

  // ---- transp role ----
  {
    const int idx = bid - 1536;
    const int b = idx & 63, fg = idx >> 6;   // fg: feature group of 32
    #pragma unroll
    for (int pass = 0; pass < 4; pass++){
      const int n  = pass*64 + (t>>2);
      const int f8 = (t&3)*8;
      const half8v v = *(const half8v*)(Hc + (size_t)(b*NN + n)*FOUT + fg*32 + f8);
      #pragma unroll
      for (int e = 0; e < 8; e++) tile[f8+e][n] = v[e];
    }
    __syncthreads();
    const int f = t>>3, ch = t&7;
    _Float16* dst = HcT + ((size_t)b*FOUT + fg*32 + f)*NN + ch*32;
    #pragma unroll
    for (int k = 0; k < 4; k++)
      *(half8v*)(dst + k*8) = *(const half8v*)(&tile[f][ch*32 + k*8]);
  }
}

// ---------------------------------------------------------------------------
// scan (R14 structure, proven 390 µs — UNTOUCHED this round).
// Model: ~1960 cyc/iter MFMA pipe (400 MFMAs/block/iter, 16x replication
// waste — floor ~210 µs, invariant to batching layouts) + ~180 µs stalls.
// ---------------------------------------------------------------------------
#define OFF_BT   0
#define OFF_DT   33280
#define OFF_HNT  53760
#define OFF_XP32 74240
#define OFF_XP8  75264
#define OFF_P8   75520
#define OFF_Z    75776
#define OFF_PM   76800
#define OFF_MASK 77824
#define OFF_DINV 86016
#define SCAN_LDS 87040

__global__ __launch_bounds__(512, 2)
void scan_kernel(
    const _Float16* __restrict__ Hc,    // [B*N][256] f16 = h_e (row-major)
    const _Float16* __restrict__ HcT,   // [B][256 feat][256 node] f16
    const _Float16* __restrict__ OUTX,  // [B*N][768] f16: [iou_x ; cou_x]
    const unsigned char* __restrict__ iouh8,  // swizzled fp8 [512][256]
    const unsigned char* __restrict__ couh8,  // swizzled fp8 [256][256]
    const float* __restrict__ invrs_iou,      // [512]
    const float* __restrict__ invrs_cou,      // [256]
    const float* __restrict__ dinv,     // [B*N]
    const unsigned int* __restrict__ maskw, // [B*N][8]
    const float* __restrict__ iouh_b,   // [512]
    const float* __restrict__ couh_b,   // [256]
    const float* __restrict__ fc_W,     // [2][256]
    const float* __restrict__ fc_b,     // [2]
    float* __restrict__ out)            // [B][2]
{
  const int b    = blockIdx.x;
  const int t    = threadIdx.x;        // 0..511
  const int wave = t >> 6;             // 0..7
  const int lane = t & 63;
  const int q    = lane >> 4;          // k-octet within MFMA frags
  const int r    = lane & 15;          // row/col index within MFMA tile
  const int f0   = 32*wave;            // wave's feature-slice base

  extern __shared__ __align__(16) char smem[];
  float*         sh_xp32 = (float*)(smem + OFF_XP32);
  unsigned char* sh_xp8  = (unsigned char*)(smem + OFF_XP8);
  unsigned char* sh_p8   = (unsigned char*)(smem + OFF_P8);
  float*         sh_z    = (float*)(smem + OFF_Z);
  float*         sh_pm   = (float*)(smem + OFF_PM);
  unsigned int*  sh_mask = (unsigned int*)(smem + OFF_MASK);
  float*         sh_dinv = (float*)(smem + OFF_DINV);

  // ---- one-time staging: zero delta-tile (5120 dw), mask words, dinv ----
  #pragma unroll
  for (int k = 0; k < 10; k++)
    ((unsigned int*)(smem + OFF_DT))[k*512 + t] = 0u;
  {
    const unsigned int* mg = maskw + ((size_t)b*NN)*8;
    #pragma unroll
    for (int k = 0; k < 4; k++) sh_mask[k*512 + t] = mg[k*512 + t];
    if (t < 256) sh_dinv[t] = dinv[(size_t)b*NN + t];
  }

  // ---- Hreg[g][ks]: H^T[f0+16g+r][ks*32 + q*8 + e] (64 VGPR) ----
  half8v Hreg[2][8];
  #pragma unroll
  for (int g = 0; g < 2; g++){
    const _Float16* hp = HcT + ((size_t)b*FOUT + f0 + 16*g + r)*NN + q*8;
    #pragma unroll
    for (int ks = 0; ks < 8; ks++)
      Hreg[g][ks] = *(const half8v*)(hp + ks*32);
  }

  // ---- recurrent weight frags (loop-invariant; 64+32 VGPR) ----
  long long ifrag[4][8];
  #pragma unroll
  for (int tt = 0; tt < 4; tt++)
    #pragma unroll
    for (int kc = 0; kc < 8; kc++)
      ifrag[tt][kc] = *(const long long*)(iouh8 + (size_t)(((4*wave+tt)*8 + kc)*512) + q*128 + r*8);
  long long cfrag[2][8];
  #pragma unroll
  for (int tt = 0; tt < 2; tt++)
    #pragma unroll
    for (int kc = 0; kc < 8; kc++)
      cfrag[tt][kc] = *(const long long*)(couh8 + (size_t)(((2*wave+tt)*8 + kc)*512) + q*128 + r*8);

  // ---- per-lane output assignments ----
  const int o1    = 64*wave + 16*(r>>2) + q*4 + (r&3);       // iou: 1/lane
  const int o_upd = 32*wave + 16*((r>>2)&1) + q*4 + (r&3);   // cou: lanes r<8
  const float bi1 = iouh_b[o1];
  const float vi1 = invrs_iou[o1];
  const float bcou_l = couh_b[o_upd];
  const float invc_l = invrs_cou[o_upd];
  float pmax = -1e30f;

  __syncthreads();   // staging done
  unsigned int wl_cur = sh_mask[0];

  #pragma unroll 1
  for (int i = 0; i < NN; i++){
    const size_t row = (size_t)b*NN + i;

    // ======== tile boundary (no barrier: all edges same-wave) ========
    if ((i & 31) == 0){
      const int tile = i >> 5;
      if (tile > 0){
        const int tprev = tile - 1;
        #pragma unroll
        for (int g = 0; g < 2; g++){
          const half8v hv = *(const half8v*)(smem + OFF_HNT + (f0 + 16*g + r)*80 + q*16);
          #pragma unroll
          for (int ks = 0; ks < 8; ks++) if (ks == tprev) Hreg[g][ks] = hv;
        }
      }
      float4v bacc[2][2];
      #pragma unroll
      for (int rt = 0; rt < 2; rt++)
        #pragma unroll
        for (int g = 0; g < 2; g++) bacc[rt][g] = (float4v){0.f,0.f,0.f,0.f};
      #pragma unroll
      for (int rt = 0; rt < 2; rt++){
        #pragma unroll
        for (int ks = 0; ks < 8; ks++){
          const unsigned int wm = sh_mask[(i + rt*16 + r)*8 + ks];
          half8v am;
          #pragma unroll
          for (int e = 0; e < 8; e++)
            am[e] = (_Float16)((wm >> (q*8 + e)) & 1u);
          bacc[rt][0] = mfma_f16(am, Hreg[0][ks], bacc[rt][0]);
          bacc[rt][1] = mfma_f16(am, Hreg[1][ks], bacc[rt][1]);
        }
      }
      #pragma unroll
      for (int rt = 0; rt < 2; rt++)
        #pragma unroll
        for (int g = 0; g < 2; g++)
          #pragma unroll
          for (int jj = 0; jj < 4; jj++)
            *(float*)(smem + (rt*16 + q*4 + jj)*1040 + (f0 + 16*g + r)*4) = bacc[rt][g][jj];
    }
    // ================================================================

    const int li = i & 31;
    const unsigned int wl_next = sh_mask[((i+1)&255)*8 + (((i+1)>>5)&7)];
    const float oxi = (float)OUTX[row*768 + o1];
    const float oxc = (float)OUTX[row*768 + 512 + o_upd];
    const float he  = (float)Hc[row*FOUT + o_upd];
    const float dv  = sh_dinv[i];

    // ---- agg: 2 K=32 correction MFMAs + B_tile (all same-wave inputs) ----
    {
      const unsigned int wl = wl_cur & ((1u << li) - 1u);  // li==0 -> 0
      half8v af;
      #pragma unroll
      for (int e = 0; e < 8; e++)
        af[e] = (_Float16)((wl >> (q*8 + e)) & 1u);
      #pragma unroll
      for (int g = 0; g < 2; g++){
        const int fg = f0 + 16*g + r;
        const half8v bf = *(const half8v*)(smem + OFF_DT + fg*80 + q*16);
        float4v ag = (float4v){0.f,0.f,0.f,0.f};
        ag = mfma_f16(af, bf, ag);
        const float bt = *(const float*)(smem + li*1040 + fg*4);
        const float xp = (bt + ag[0]) * dv;
        if (q == 0)      sh_xp32[fg] = xp;
        else if (q == 1) sh_xp8[fg] = enc8(xp * 16.f);
      }
    }
    wl_cur = wl_next;
    __syncthreads();                                    // B2 (xp cross-wave)

    // ---- iou matvec: 32 fp8 MFMAs, 1 sigmoid/lane ----
    {
      float4v iacc[4];
      #pragma unroll
      for (int tt = 0; tt < 4; tt++) iacc[tt] = (float4v){0.f,0.f,0.f,0.f};
      #pragma unroll
      for (int kc = 0; kc < 8; kc++){
        const long long bfr = *(const long long*)(sh_xp8 + kc*32 + q*8);
        #pragma unroll
        for (int tt = 0; tt < 4; tt++)
          iacc[tt] = mfma_fp8(ifrag[tt][kc], bfr, iacc[tt]);
      }
      float d1 = 0.f;
      #pragma unroll
      for (int tt = 0; tt < 4; tt++) if ((r>>2) == tt){
        #pragma unroll
        for (int jj = 0; jj < 4; jj++) if ((r&3) == jj) d1 = iacc[tt][jj];
      }
      const float g1 = d1*vi1 + oxi + bi1;
      const float sg = 1.f / (1.f + __expf(-g1));
      if (wave < 4) sh_p8[o1] = enc8(sg * sh_xp32[o1] * 16.f);  // r-gates
      else          sh_z[o1 - 256] = sg;                        // z-gates
    }
    __syncthreads();                                    // B3 (p8/z cross-wave)

    // ---- cou matvec: 16 fp8 MFMAs + fused update (lanes r<8) ----
    {
      float4v cacc[2];
      cacc[0] = (float4v){0.f,0.f,0.f,0.f};
      cacc[1] = cacc[0];
      #pragma unroll
      for (int kc = 0; kc < 8; kc++){
        const long long bfr = *(const long long*)(sh_p8 + kc*32 + q*8);
        cacc[0] = mfma_fp8(cfrag[0][kc], bfr, cacc[0]);
        cacc[1] = mfma_fp8(cfrag[1][kc], bfr, cacc[1]);
      }
      if (r < 8){
        float cd = 0.f;
        #pragma unroll
        for (int tt = 0; tt < 2; tt++) if ((r>>2) == tt){
          #pragma unroll
          for (int jj = 0; jj < 4; jj++) if ((r&3) == jj) cd = cacc[tt][jj];
        }
        const float v   = cd*invc_l + oxc + bcou_l;
        const float hcv = tanhf(v);
        const float z   = sh_z[o_upd];
        const float xpv = sh_xp32[o_upd];
        const float hn  = z*xpv + (1.f - z)*hcv;
        pmax = fmaxf(pmax, hn);
        *(_Float16*)(smem + OFF_DT  + o_upd*80 + li*2) = (_Float16)(hn - he);
        *(_Float16*)(smem + OFF_HNT + o_upd*80 + li*2) = (_Float16)hn;
      }
    }
    // no B4: dT/hnT consumed same-wave; xp/p8/z overwrites fenced by B2/B3
  }

  // ---- epilogue: pooled max -> fc ----
  if (r < 8) sh_pm[o_upd] = pmax;
  __syncthreads();
  if (t < 128){
    const int c = t >> 6;   // 0 or 1
    float s = 0.f;
    #pragma unroll
    for (int qq = 0; qq < 4; qq++){
      const int f = (t & 63) + qq*64;
      s += fc_W[c*256 + f] * sh_pm[f];
    }
    #pragma unroll
    for (int off = 32; off > 0; off >>= 1) s += __shfl_xor(s, off, 64);
    if ((t & 63) == 0) out[b*2 + c] = s + fc_b[c];
  }
}

// ---------------------------------------------------------------------------
extern "C" void kernel_launch(void* const* d_in, const int* in_sizes, int n_in,
                              void* d_out, int out_size, void* d_ws, size_t ws_size,
                              hipStream_t stream)
{
  (void)in_sizes; (void)n_in; (void)out_size; (void)ws_size;
  const float* h      = (const float*)d_in[0];
  const float* adj    = (const float*)d_in[1];
  const float* emb_W  = (const float*)d_in[2];
  const float* ioux_W = (const float*)d_in[3];
  const float* ioux_b = (const float*)d_in[4];
  const float* iouh_W = (const float*)d_in[5];
  const float* iouh_b = (const float*)d_in[6];
  const float* coux_W = (const float*)d_in[7];
  const float* coux_b = (const float*)d_in[8];
  const float* couh_W = (const float*)d_in[9];
  const float* couh_b = (const float*)d_in[10];
  const float* fc_W   = (const float*)d_in[11];
  const float* fc_b   = (const float*)d_in[12];
  float* out = (float*)d_out;

  // ---- carve workspace (256B aligned chunks) ----
  size_t off = 0;
  char* base = (char*)d_ws;
  auto carve = [&](size_t bytes)->char* {
    off = (off + 255) & ~(size_t)255;
    char* p = base + off;
    off += bytes;
    return p;
  };
  _Float16* embW16 = (_Float16*)carve((size_t)256*768*2);
  _Float16* Wcat16 = (_Float16*)carve((size_t)768*256*2);
  float*    biascat= (float*)  carve((size_t)768*4);
  unsigned char* iouh8 = (unsigned char*)carve(131072);
  unsigned char* couh8 = (unsigned char*)carve(65536);
  float*    invrs_iou = (float*)carve(512*4);
  float*    invrs_cou = (float*)carve(256*4);
  float*    dinv   = (float*)  carve((size_t)NB*NN*4);
  unsigned int* maskw = (unsigned int*)carve((size_t)NB*NN*8*4 + 64); // +pad
  _Float16* Hc     = (_Float16*)carve((size_t)NB*NN*FOUT*2);       // h_e
  _Float16* HcT    = (_Float16*)carve((size_t)NB*NN*FOUT*2);       // h_e^T
  _Float16* OUTX   = (_Float16*)carve((size_t)NB*NN*768*2);        // [iou_x;cou_x]

  // raise dynamic LDS cap for the scan kernel (idempotent, non-stream op)
  hipFuncSetAttribute((const void*)scan_kernel,
                      hipFuncAttributeMaxDynamicSharedMemorySize, SCAN_LDS);

  // 1) fused setup: prep + quant + degmask (independent, one launch)
  setup_kernel<<<dim3(2371), dim3(256), 0, stream>>>(
      emb_W, ioux_W, ioux_b, coux_W, coux_b, iouh_W, couh_W, adj,
      embW16, Wcat16, biascat, iouh8, couh8, invrs_iou, invrs_cou,
      maskw, dinv);

  // 2) h_e = h @ emb_W^T  (8 col-tiles/block: f32 A read 2x instead of 4x)
  gemm16_kernel<1, 8><<<dim3(256, 2), dim3(256), 0, stream>>>(
      (const void*)h, embW16, Hc, nullptr, NB*NN, FOUT, FIN, FOUT);

  // 3) fused tail: OUTX GEMM (8 col-tiles/block) + HcT transpose
  tail_kernel<<<dim3(2048), dim3(256), 0, stream>>>(
      Hc, Wcat16, biascat, OUTX, HcT);

  // 4) sequential tree scan (R14 structure, proven 390 us)
  scan_kernel<<<dim3(NB), dim3(512), SCAN_LDS, stream>>>(
      Hc, HcT, OUTX, iouh8, couh8, invrs_iou, invrs_cou, dinv, maskw,
      iouh_b, couh_b, fc_W, fc_b, out);
}

// Round 12
// 601.694 us; speedup vs baseline: 1.2459x; 1.0242x over previous
//
#include <hip/hip_runtime.h>
#include <hip/hip_fp16.h>

// Problem constants: B=64, N=256, F_IN=768, F_OUT=256
#define NB    64
#define NN    256
#define FIN   768
#define FOUT  256

typedef _Float16 half8v __attribute__((ext_vector_type(8)));
typedef float    float4v __attribute__((ext_vector_type(4)));

// f32 -> fp8 e4m3 (OCP, RNE) single value
__device__ inline unsigned char enc8(float v){
#if __has_builtin(__builtin_amdgcn_cvt_pk_fp8_f32)
  return (unsigned char)(__builtin_amdgcn_cvt_pk_fp8_f32(v, v, 0, false) & 0xFF);
#else
  float best = 1e30f; unsigned char bc = 0;
  for (int c = 0; c < 256; c++){
    if ((c & 0x7F) == 0x7F) continue;            // NaN codes
    int e = (c >> 3) & 15, mnt = c & 7;
    float mag = e ? ldexpf(1.f + mnt*0.125f, e-7) : ldexpf(mnt*0.125f, -6);
    float d = (c >> 7) ? -mag : mag;
    float err = fabsf(v - d);
    if (err < best){ best = err; bc = (unsigned char)c; }
  }
  return bc;
#endif
}

__device__ inline float4v mfma_fp8(long long a, long long b, float4v c){
  return __builtin_amdgcn_mfma_f32_16x16x32_fp8_fp8(a, b, c, 0, 0, 0);
}
__device__ inline float4v mfma_f16(half8v a, half8v b, float4v c){
  return __builtin_amdgcn_mfma_f32_16x16x32_f16(a, b, c, 0, 0, 0);
}

// ---------------------------------------------------------------------------
// setup: fused prep + quant + degmask (mutually independent; blockIdx roles).
// ---------------------------------------------------------------------------
__global__ __launch_bounds__(256) void setup_kernel(
    const float* __restrict__ emb_W, const float* __restrict__ ioux_W,
    const float* __restrict__ ioux_b, const float* __restrict__ coux_W,
    const float* __restrict__ coux_b,
    const float* __restrict__ iouh_W, const float* __restrict__ couh_W,
    const float* __restrict__ adj,
    _Float16* __restrict__ embW16, _Float16* __restrict__ Wcat16,
    float* __restrict__ biascat,
    unsigned char* __restrict__ iouh8, unsigned char* __restrict__ couh8,
    float* __restrict__ invrs_iou, float* __restrict__ invrs_cou,
    unsigned int* __restrict__ maskw, float* __restrict__ dinv)
{
  __shared__ float sm[256];               // quant reduction
  __shared__ unsigned int rb[256][8];     // degmask bit-transpose
  const int bid = blockIdx.x;
  const int t   = threadIdx.x;

  if (bid < 1539){
    // ---- prep role ----
    int idx = bid*256 + t;
    if (idx < 196608) { embW16[idx] = (_Float16)emb_W[idx]; return; }
    idx -= 196608;
    if (idx < 196608) {
      int o = idx >> 8, k = idx & 255;
      float v = (o < 512) ? ioux_W[o*256 + k] : coux_W[(o-512)*256 + k];
      Wcat16[idx] = (_Float16)v; return;
    }
    idx -= 196608;
    if (idx < 768) biascat[idx] = (idx < 512) ? ioux_b[idx] : coux_b[idx-512];
    return;
  }

  if (bid < 2307){
    // ---- quant role ----
    const int row = bid - 1539;           // 0..767
    const bool is_iou = (row < 512);
    const int rl = is_iou ? row : row - 512;
    const float w = is_iou ? iouh_W[(size_t)rl*256 + t] : couh_W[(size_t)rl*256 + t];
    sm[t] = fabsf(w);
    __syncthreads();
    for (int s = 128; s > 0; s >>= 1){
      if (t < s) sm[t] = fmaxf(sm[t], sm[t+s]);
      __syncthreads();
    }
    const float mx = sm[0];
    const float rs = (mx > 1e-20f) ? (240.0f / mx) : 1.0f;
    const unsigned char byte = enc8(w * rs);
    const int off = ((rl>>4)*8 + (t>>5))*512 + ((t>>3)&3)*128 + (rl&15)*8 + (t&7);
    if (is_iou) iouh8[off] = byte; else couh8[off] = byte;
    if (t == 0){
      const float inv = 1.0f / (rs * 16.0f);
      if (is_iou) invrs_iou[rl] = inv; else invrs_cou[rl] = inv;
    }
    return;
  }

  // ---- degmask role: one row-major read + LDS bit transpose ----
  {
    const int b = bid - 2307;
    const float* rowp = adj + (size_t)b*NN*NN + (size_t)t*NN;
    float s = 0.f;
    #pragma unroll
    for (int qc = 0; qc < 8; qc++){
      unsigned int w = 0;
      const float4* rp = (const float4*)(rowp + qc*32);
      #pragma unroll
      for (int j4 = 0; j4 < 8; j4++){
        float4 v = rp[j4];
        s += v.x + v.y + v.z + v.w;
        const int sh = j4*4;
        w |= (v.x != 0.f ? 1u : 0u) << sh;
        w |= (v.y != 0.f ? 1u : 0u) << (sh+1);
        w |= (v.z != 0.f ? 1u : 0u) << (sh+2);
        w |= (v.w != 0.f ? 1u : 0u) << (sh+3);
      }
      rb[t][qc] = w;
    }
    dinv[b*NN + t] = (s != 0.f) ? 1.0f/s : 0.0f;
    __syncthreads();
    #pragma unroll
    for (int qc = 0; qc < 8; qc++){
      unsigned int w = 0;
      #pragma unroll
      for (int jj = 0; jj < 32; jj++)
        w |= ((rb[qc*32 + jj][t>>5] >> (t&31)) & 1u) << jj;
      maskw[((size_t)b*NN + t)*8 + qc] = w;
    }
  }
}

// ---------------------------------------------------------------------------
// mid: fused {Hc = h @ embW^T} + {OUTX = Hc @ Wcat^T + bias} + {HcT slice}.
// R19: gemm4's 64-row block slab = exactly what tail consumed. Block keeps
// its Hc tile in LDS -> OUTX GEMM reads LDS (kills 50MB global Hc re-reads
// + per-step L2 latency), transpose absorbed. 256 blocks x 512 thr (8 waves,
// 2/SIMD). Phase1: waves (rgrp 0..3, cseg 0..1) cover 16 rows x 128 cols,
// K=768. Phase2: same rows, 384 OUTX cols per wave in 3 passes, K=256 from
// LDS. Phase3: HcT[b][f][block-rows] from LDS, 64B-contig stores.
// Numerics identical to R18 (same f16 values, same K-order).
// ---------------------------------------------------------------------------
__global__ __launch_bounds__(512) void mid_kernel(
    const float* __restrict__ h, const _Float16* __restrict__ embW16,
    const _Float16* __restrict__ Wcat16, const float* __restrict__ biascat,
    _Float16* __restrict__ Hc, _Float16* __restrict__ OUTX,
    _Float16* __restrict__ HcT)
{
  __shared__ _Float16 lds_hc[64][264];    // 64 rows x 256 cols (+8 pad)
  const int bx   = blockIdx.x;            // 0..255: rows [bx*64, +64)
  const int t    = threadIdx.x;           // 0..511
  const int wave = t >> 6;
  const int lane = t & 63;
  const int rgrp = wave & 3;              // row group of 16
  const int cseg = wave >> 2;             // 0/1: col segment
  const int m0g  = bx*64;
  const int mrow = m0g + rgrp*16 + (lane & 15);
  const int kgrp = lane >> 4;

  // ---- phase 1: Hc rows = h @ embW^T (cols cseg*128..+128) ----
  {
    float4v acc[8];
    #pragma unroll
    for (int nt = 0; nt < 8; nt++) acc[nt] = (float4v){0.f,0.f,0.f,0.f};
    for (int k0 = 0; k0 < FIN; k0 += 32){
      const int ka = k0 + kgrp*8;
      const float4* ap = (const float4*)(h + (size_t)mrow*FIN + ka);
      float4 a0 = ap[0], a1 = ap[1];
      half8v af;
      af[0]=(_Float16)a0.x; af[1]=(_Float16)a0.y; af[2]=(_Float16)a0.z; af[3]=(_Float16)a0.w;
      af[4]=(_Float16)a1.x; af[5]=(_Float16)a1.y; af[6]=(_Float16)a1.z; af[7]=(_Float16)a1.w;
      #pragma unroll
      for (int nt = 0; nt < 8; nt++){
        const int ncol = cseg*128 + nt*16 + (lane & 15);
        const half8v bf = *(const half8v*)(embW16 + (size_t)ncol*FIN + ka);
        acc[nt] = mfma_f16(af, bf, acc[nt]);
      }
    }
    #pragma unroll
    for (int nt = 0; nt < 8; nt++){
      const int ncol = cseg*128 + nt*16 + (lane & 15);
      #pragma unroll
      for (int r4 = 0; r4 < 4; r4++){
        const int ol = rgrp*16 + (lane>>4)*4 + r4;    // local row 0..63
        const _Float16 v = (_Float16)acc[nt][r4];
        lds_hc[ol][ncol] = v;
        Hc[(size_t)(m0g + ol)*FOUT + ncol] = v;
      }
    }
  }
  __syncthreads();

  // ---- phase 2: OUTX rows = HcTile(LDS) @ Wcat^T + bias ----
  {
    const int lrow = rgrp*16 + (lane & 15);
    #pragma unroll
    for (int pass = 0; pass < 3; pass++){
      const int oc0 = cseg*384 + pass*128;
      float4v acc[8];
      #pragma unroll
      for (int nt = 0; nt < 8; nt++) acc[nt] = (float4v){0.f,0.f,0.f,0.f};
      for (int k0 = 0; k0 < FOUT; k0 += 32){
        const int ka = k0 + kgrp*8;
        const half8v af = *(const half8v*)(&lds_hc[lrow][ka]);
        #pragma unroll
        for (int nt = 0; nt < 8; nt++){
          const int ncol = oc0 + nt*16 + (lane & 15);
          const half8v bf = *(const half8v*)(Wcat16 + (size_t)ncol*FOUT + ka);
          acc[nt] = mfma_f16(af, bf, acc[nt]);
        }
      }
      #pragma unroll
      for (int nt = 0; nt < 8; nt++){
        const int ncol = oc0 + nt*16 + (lane & 15);
        const float bv = biascat[ncol];
        #pragma unroll
        for (int r4 = 0; r4 < 4; r4++){
          const int orow = m0g + rgrp*16 + (lane>>4)*4 + r4;
          OUTX[(size_t)orow*768 + ncol] = (_Float16)(acc[nt][r4] + bv);
        }
      }
    }
  }

  // ---- phase 3: HcT[b][f][n-range] from LDS (64B contiguous per thread) ----
  {
    const int b  = bx >> 2;
    const int n0 = (bx & 3)*64;
    const int f  = t >> 1;        // 0..255
    const int ch = t & 1;         // half of 64 rows
    unsigned short buf[32];
    #pragma unroll
    for (int j = 0; j < 32; j++){
      union { _Float16 hv; unsigned short u; } cv;
      cv.hv = lds_hc[ch*32 + j][f];
      buf[j] = cv.u;
    }
    _Float16* dst = HcT + ((size_t)b*FOUT + f)*NN + n0 + ch*32;
    #pragma unroll
    for (int k = 0; k < 4; k++)
      *(uint4*)((char*)dst + k*16) = *(const uint4*)(&buf[k*8]);
  }
}

// ---------------------------------------------------------------------------
// scan (R14 structure, proven 390 µs — UNTOUCHED).
// Model: ~1940 cyc/iter MFMA pipe (400 MFMAs/block/iter; 16x N-replication
// waste is inherent to matvec-on-MFMA at K=32) + ~1700 cyc stalls.
// ---------------------------------------------------------------------------
#define OFF_BT   0
#define OFF_DT   33280
#define OFF_HNT  53760
#define OFF_XP32 74240
#define OFF_XP8  75264
#define OFF_P8   75520
#define OFF_Z    75776
#define OFF_PM   76800
#define OFF_MASK 77824
#define OFF_DINV 86016
#define SCAN_LDS 87040

__global__ __launch_bounds__(512, 2)
void scan_kernel(
    const _Float16* __restrict__ Hc,    // [B*N][256] f16 = h_e (row-major)
    const _Float16* __restrict__ HcT,   // [B][256 feat][256 node] f16
    const _Float16* __restrict__ OUTX,  // [B*N][768] f16: [iou_x ; cou_x]
    const unsigned char* __restrict__ iouh8,  // swizzled fp8 [512][256]
    const unsigned char* __restrict__ couh8,  // swizzled fp8 [256][256]
    const float* __restrict__ invrs_iou,      // [512]
    const float* __restrict__ invrs_cou,      // [256]
    const float* __restrict__ dinv,     // [B*N]
    const unsigned int* __restrict__ maskw, // [B*N][8]
    const float* __restrict__ iouh_b,   // [512]
    const float* __restrict__ couh_b,   // [256]
    const float* __restrict__ fc_W,     // [2][256]
    const float* __restrict__ fc_b,     // [2]
    float* __restrict__ out)            // [B][2]
{
  const int b    = blockIdx.x;
  const int t    = threadIdx.x;        // 0..511
  const int wave = t >> 6;             // 0..7
  const int lane = t & 63;
  const int q    = lane >> 4;          // k-octet within MFMA frags
  const int r    = lane & 15;          // row/col index within MFMA tile
  const int f0   = 32*wave;            // wave's feature-slice base

  extern __shared__ __align__(16) char smem[];
  float*         sh_xp32 = (float*)(smem + OFF_XP32);
  unsigned char* sh_xp8  = (unsigned char*)(smem + OFF_XP8);
  unsigned char* sh_p8   = (unsigned char*)(smem + OFF_P8);
  float*         sh_z    = (float*)(smem + OFF_Z);
  float*         sh_pm   = (float*)(smem + OFF_PM);
  unsigned int*  sh_mask = (unsigned int*)(smem + OFF_MASK);
  float*         sh_dinv = (float*)(smem + OFF_DINV);

  // ---- one-time staging: zero delta-tile (5120 dw), mask words, dinv ----
  #pragma unroll
  for (int k = 0; k < 10; k++)
    ((unsigned int*)(smem + OFF_DT))[k*512 + t] = 0u;
  {
    const unsigned int* mg = maskw + ((size_t)b*NN)*8;
    #pragma unroll
    for (int k = 0; k < 4; k++) sh_mask[k*512 + t] = mg[k*512 + t];
    if (t < 256) sh_dinv[t] = dinv[(size_t)b*NN + t];
  }

  // ---- Hreg[g][ks]: H^T[f0+16g+r][ks*32 + q*8 + e] (64 VGPR) ----
  half8v Hreg[2][8];
  #pragma unroll
  for (int g = 0; g < 2; g++){
    const _Float16* hp = HcT + ((size_t)b*FOUT + f0 + 16*g + r)*NN + q*8;
    #pragma unroll
    for (int ks = 0; ks < 8; ks++)
      Hreg[g][ks] = *(const half8v*)(hp + ks*32);
  }

  // ---- recurrent weight frags (loop-invariant; 64+32 VGPR) ----
  long long ifrag[4][8];
  #pragma unroll
  for (int tt = 0; tt < 4; tt++)
    #pragma unroll
    for (int kc = 0; kc < 8; kc++)
      ifrag[tt][kc] = *(const long long*)(iouh8 + (size_t)(((4*wave+tt)*8 + kc)*512) + q*128 + r*8);
  long long cfrag[2][8];
  #pragma unroll
  for (int tt = 0; tt < 2; tt++)
    #pragma unroll
    for (int kc = 0; kc < 8; kc++)
      cfrag[tt][kc] = *(const long long*)(couh8 + (size_t)(((2*wave+tt)*8 + kc)*512) + q*128 + r*8);

  // ---- per-lane output assignments ----
  const int o1    = 64*wave + 16*(r>>2) + q*4 + (r&3);       // iou: 1/lane
  const int o_upd = 32*wave + 16*((r>>2)&1) + q*4 + (r&3);   // cou: lanes r<8
  const float bi1 = iouh_b[o1];
  const float vi1 = invrs_iou[o1];
  const float bcou_l = couh_b[o_upd];
  const float invc_l = invrs_cou[o_upd];
  float pmax = -1e30f;

  __syncthreads();   // staging done
  unsigned int wl_cur = sh_mask[0];

  #pragma unroll 1
  for (int i = 0; i < NN; i++){
    const size_t row = (size_t)b*NN + i;

    // ======== tile boundary (no barrier: all edges same-wave) ========
    if ((i & 31) == 0){
      const int tile = i >> 5;
      if (tile > 0){
        const int tprev = tile - 1;
        #pragma unroll
        for (int g = 0; g < 2; g++){
          const half8v hv = *(const half8v*)(smem + OFF_HNT + (f0 + 16*g + r)*80 + q*16);
          #pragma unroll
          for (int ks = 0; ks < 8; ks++) if (ks == tprev) Hreg[g][ks] = hv;
        }
      }
      float4v bacc[2][2];
      #pragma unroll
      for (int rt = 0; rt < 2; rt++)
        #pragma unroll
        for (int g = 0; g < 2; g++) bacc[rt][g] = (float4v){0.f,0.f,0.f,0.f};
      #pragma unroll
      for (int rt = 0; rt < 2; rt++){
        #pragma unroll
        for (int ks = 0; ks < 8; ks++){
          const unsigned int wm = sh_mask[(i + rt*16 + r)*8 + ks];
          half8v am;
          #pragma unroll
          for (int e = 0; e < 8; e++)
            am[e] = (_Float16)((wm >> (q*8 + e)) & 1u);
          bacc[rt][0] = mfma_f16(am, Hreg[0][ks], bacc[rt][0]);
          bacc[rt][1] = mfma_f16(am, Hreg[1][ks], bacc[rt][1]);
        }
      }
      #pragma unroll
      for (int rt = 0; rt < 2; rt++)
        #pragma unroll
        for (int g = 0; g < 2; g++)
          #pragma unroll
          for (int jj = 0; jj < 4; jj++)
            *(float*)(smem + (rt*16 + q*4 + jj)*1040 + (f0 + 16*g + r)*4) = bacc[rt][g][jj];
    }
    // ================================================================

    const int li = i & 31;
    const unsigned int wl_next = sh_mask[((i+1)&255)*8 + (((i+1)>>5)&7)];
    const float oxi = (float)OUTX[row*768 + o1];
    const float oxc = (float)OUTX[row*768 + 512 + o_upd];
    const float he  = (float)Hc[row*FOUT + o_upd];
    const float dv  = sh_dinv[i];

    // ---- agg: 2 K=32 correction MFMAs + B_tile (all same-wave inputs) ----
    {
      const unsigned int wl = wl_cur & ((1u << li) - 1u);  // li==0 -> 0
      half8v af;
      #pragma unroll
      for (int e = 0; e < 8; e++)
        af[e] = (_Float16)((wl >> (q*8 + e)) & 1u);
      #pragma unroll
      for (int g = 0; g < 2; g++){
        const int fg = f0 + 16*g + r;
        const half8v bf = *(const half8v*)(smem + OFF_DT + fg*80 + q*16);
        float4v ag = (float4v){0.f,0.f,0.f,0.f};
        ag = mfma_f16(af, bf, ag);
        const float bt = *(const float*)(smem + li*1040 + fg*4);
        const float xp = (bt + ag[0]) * dv;
        if (q == 0)      sh_xp32[fg] = xp;
        else if (q == 1) sh_xp8[fg] = enc8(xp * 16.f);
      }
    }
    wl_cur = wl_next;
    __syncthreads();                                    // B2 (xp cross-wave)

    // ---- iou matvec: 32 fp8 MFMAs, 1 sigmoid/lane ----
    {
      float4v iacc[4];
      #pragma unroll
      for (int tt = 0; tt < 4; tt++) iacc[tt] = (float4v){0.f,0.f,0.f,0.f};
      #pragma unroll
      for (int kc = 0; kc < 8; kc++){
        const long long bfr = *(const long long*)(sh_xp8 + kc*32 + q*8);
        #pragma unroll
        for (int tt = 0; tt < 4; tt++)
          iacc[tt] = mfma_fp8(ifrag[tt][kc], bfr, iacc[tt]);
      }
      float d1 = 0.f;
      #pragma unroll
      for (int tt = 0; tt < 4; tt++) if ((r>>2) == tt){
        #pragma unroll
        for (int jj = 0; jj < 4; jj++) if ((r&3) == jj) d1 = iacc[tt][jj];
      }
      const float g1 = d1*vi1 + oxi + bi1;
      const float sg = 1.f / (1.f + __expf(-g1));
      if (wave < 4) sh_p8[o1] = enc8(sg * sh_xp32[o1] * 16.f);  // r-gates
      else          sh_z[o1 - 256] = sg;                        // z-gates
    }
    __syncthreads();                                    // B3 (p8/z cross-wave)

    // ---- cou matvec: 16 fp8 MFMAs + fused update (lanes r<8) ----
    {
      float4v cacc[2];
      cacc[0] = (float4v){0.f,0.f,0.f,0.f};
      cacc[1] = cacc[0];
      #pragma unroll
      for (int kc = 0; kc < 8; kc++){
        const long long bfr = *(const long long*)(sh_p8 + kc*32 + q*8);
        cacc[0] = mfma_fp8(cfrag[0][kc], bfr, cacc[0]);
        cacc[1] = mfma_fp8(cfrag[1][kc], bfr, cacc[1]);
      }
      if (r < 8){
        float cd = 0.f;
        #pragma unroll
        for (int tt = 0; tt < 2; tt++) if ((r>>2) == tt){
          #pragma unroll
          for (int jj = 0; jj < 4; jj++) if ((r&3) == jj) cd = cacc[tt][jj];
        }
        const float v   = cd*invc_l + oxc + bcou_l;
        const float hcv = tanhf(v);
        const float z   = sh_z[o_upd];
        const float xpv = sh_xp32[o_upd];
        const float hn  = z*xpv + (1.f - z)*hcv;
        pmax = fmaxf(pmax, hn);
        *(_Float16*)(smem + OFF_DT  + o_upd*80 + li*2) = (_Float16)(hn - he);
        *(_Float16*)(smem + OFF_HNT + o_upd*80 + li*2) = (_Float16)hn;
      }
    }
    // no B4: dT/hnT consumed same-wave; xp/p8/z overwrites fenced by B2/B3
  }

  // ---- epilogue: pooled max -> fc ----
  if (r < 8) sh_pm[o_upd] = pmax;
  __syncthreads();
  if (t < 128){
    const int c = t >> 6;   // 0 or 1
    float s = 0.f;
    #pragma unroll
    for (int qq = 0; qq < 4; qq++){
      const int f = (t & 63) + qq*64;
      s += fc_W[c*256 + f] * sh_pm[f];
    }
    #pragma unroll
    for (int off = 32; off > 0; off >>= 1) s += __shfl_xor(s, off, 64);
    if ((t & 63) == 0) out[b*2 + c] = s + fc_b[c];
  }
}

// ---------------------------------------------------------------------------
extern "C" void kernel_launch(void* const* d_in, const int* in_sizes, int n_in,
                              void* d_out, int out_size, void* d_ws, size_t ws_size,
                              hipStream_t stream)
{
  (void)in_sizes; (void)n_in; (void)out_size; (void)ws_size;
  const float* h      = (const float*)d_in[0];
  const float* adj    = (const float*)d_in[1];
  const float* emb_W  = (const float*)d_in[2];
  const float* ioux_W = (const float*)d_in[3];
  const float* ioux_b = (const float*)d_in[4];
  const float* iouh_W = (const float*)d_in[5];
  const float* iouh_b = (const float*)d_in[6];
  const float* coux_W = (const float*)d_in[7];
  const float* coux_b = (const float*)d_in[8];
  const float* couh_W = (const float*)d_in[9];
  const float* couh_b = (const float*)d_in[10];
  const float* fc_W   = (const float*)d_in[11];
  const float* fc_b   = (const float*)d_in[12];
  float* out = (float*)d_out;

  // ---- carve workspace (256B aligned chunks) ----
  size_t off = 0;
  char* base = (char*)d_ws;
  auto carve = [&](size_t bytes)->char* {
    off = (off + 255) & ~(size_t)255;
    char* p = base + off;
    off += bytes;
    return p;
  };
  _Float16* embW16 = (_Float16*)carve((size_t)256*768*2);
  _Float16* Wcat16 = (_Float16*)carve((size_t)768*256*2);
  float*    biascat= (float*)  carve((size_t)768*4);
  unsigned char* iouh8 = (unsigned char*)carve(131072);
  unsigned char* couh8 = (unsigned char*)carve(65536);
  float*    invrs_iou = (float*)carve(512*4);
  float*    invrs_cou = (float*)carve(256*4);
  float*    dinv   = (float*)  carve((size_t)NB*NN*4);
  unsigned int* maskw = (unsigned int*)carve((size_t)NB*NN*8*4 + 64); // +pad
  _Float16* Hc     = (_Float16*)carve((size_t)NB*NN*FOUT*2);       // h_e
  _Float16* HcT    = (_Float16*)carve((size_t)NB*NN*FOUT*2);       // h_e^T
  _Float16* OUTX   = (_Float16*)carve((size_t)NB*NN*768*2);        // [iou_x;cou_x]

  // raise dynamic LDS cap for the scan kernel (idempotent, non-stream op)
  hipFuncSetAttribute((const void*)scan_kernel,
                      hipFuncAttributeMaxDynamicSharedMemorySize, SCAN_LDS);

  // 1) fused setup: prep + quant + degmask (independent, one launch)
  setup_kernel<<<dim3(2371), dim3(256), 0, stream>>>(
      emb_W, ioux_W, ioux_b, coux_W, coux_b, iouh_W, couh_W, adj,
      embW16, Wcat16, biascat, iouh8, couh8, invrs_iou, invrs_cou,
      maskw, dinv);

  // 2) fused mid: Hc GEMM + OUTX GEMM (from LDS) + HcT transpose
  mid_kernel<<<dim3(256), dim3(512), 0, stream>>>(
      h, embW16, Wcat16, biascat, Hc, OUTX, HcT);

  // 3) sequential tree scan (R14 structure, proven 390 us)
  scan_kernel<<<dim3(NB), dim3(512), SCAN_LDS, stream>>>(
      Hc, HcT, OUTX, iouh8, couh8, invrs_iou, invrs_cou, dinv, maskw,
      iouh_b, couh_b, fc_W, fc_b, out);
}